// Round 1
// baseline (1299.117 us; speedup 1.0000x reference)
//
#include <hip/hip_runtime.h>

#define HDIM 128
#define TR 32
#define BN_EPS 1e-5f

// ---------------------------------------------------------------------------
// Scatter-add: agg[tgt[e]] += x[src[e]]  (32 threads per edge, float4 gather)
// ---------------------------------------------------------------------------
__global__ __launch_bounds__(256) void scatter_kernel(
    const float* __restrict__ x, const int* __restrict__ eidx,
    float* __restrict__ agg, int E)
{
    long tid = (long)blockIdx.x * blockDim.x + threadIdx.x;
    int e = (int)(tid >> 5);
    if (e >= E) return;
    int g = (int)(tid & 31);
    int s = eidx[e];
    int t = eidx[E + e];
    const float4 v = *(const float4*)(x + (size_t)s * HDIM + g * 4);
    float* dst = agg + (size_t)t * HDIM + g * 4;
    atomicAdd(dst + 0, v.x);
    atomicAdd(dst + 1, v.y);
    atomicAdd(dst + 2, v.z);
    atomicAdd(dst + 3, v.w);
}

// ---------------------------------------------------------------------------
// GEMM1: h1 = relu((agg + (1+eps)*x) @ W1^T + b1)
// Block: 256 threads, 32 rows x 128 cols tile. W transposed in LDS (stride 129,
// conflict-free), input rows in LDS (stride 132, float4-aligned, broadcast).
// Thread (tx,ty): cols cb=4*tx..+3, rows 4*ty..+3  -> 4x4 register tile.
// ---------------------------------------------------------------------------
__global__ __launch_bounds__(256) void gemm1_kernel(
    const float* __restrict__ agg, const float* __restrict__ x,
    const float* __restrict__ eps, const float* __restrict__ W,
    const float* __restrict__ bias, float* __restrict__ out, int N)
{
    __shared__ float sWT[HDIM * 129];   // sWT[k*129+c] = W[c*128+k]
    __shared__ float sIn[TR * 132];

    int t = threadIdx.x;
    int rb = blockIdx.x * TR;
    float coef = 1.0f + eps[0];

    // stage W transposed (global read coalesced; LDS write banks (k+c)%32 -> conflict-free)
    for (int i = t; i < HDIM * HDIM; i += 256) {
        int c = i >> 7, k = i & 127;
        sWT[k * 129 + c] = W[i];
    }
    // stage input rows: out_row = agg + coef * x
    for (int f = t; f < TR * (HDIM / 4); f += 256) {
        int r = f >> 5;
        int kg = (f & 31) * 4;
        int row = rb + r;
        float4 av;
        if (row < N) {
            av = *(const float4*)(agg + (size_t)row * HDIM + kg);
            float4 xv = *(const float4*)(x + (size_t)row * HDIM + kg);
            av.x += coef * xv.x; av.y += coef * xv.y;
            av.z += coef * xv.z; av.w += coef * xv.w;
        } else {
            av = make_float4(0.f, 0.f, 0.f, 0.f);
        }
        *(float4*)(&sIn[r * 132 + kg]) = av;
    }
    __syncthreads();

    int tx = t & 31, ty = t >> 5;
    int cb = tx * 4;
    float4 acc[4];
    #pragma unroll
    for (int i = 0; i < 4; i++) acc[i] = make_float4(0.f, 0.f, 0.f, 0.f);

    for (int k0 = 0; k0 < HDIM; k0 += 4) {
        float a[4][4];
        #pragma unroll
        for (int i = 0; i < 4; i++)
            *(float4*)a[i] = *(const float4*)(&sIn[(ty * 4 + i) * 132 + k0]);
        #pragma unroll
        for (int kk = 0; kk < 4; kk++) {
            const float* wrow = &sWT[(k0 + kk) * 129 + cb];
            float w0 = wrow[0], w1 = wrow[1], w2 = wrow[2], w3 = wrow[3];
            #pragma unroll
            for (int i = 0; i < 4; i++) {
                acc[i].x += a[i][kk] * w0;
                acc[i].y += a[i][kk] * w1;
                acc[i].z += a[i][kk] * w2;
                acc[i].w += a[i][kk] * w3;
            }
        }
    }

    float4 bb = *(const float4*)(bias + cb);
    #pragma unroll
    for (int i = 0; i < 4; i++) {
        int row = rb + ty * 4 + i;
        if (row < N) {
            float4 v;
            v.x = fmaxf(acc[i].x + bb.x, 0.f);
            v.y = fmaxf(acc[i].y + bb.y, 0.f);
            v.z = fmaxf(acc[i].z + bb.z, 0.f);
            v.w = fmaxf(acc[i].w + bb.w, 0.f);
            *(float4*)(out + (size_t)row * HDIM + cb) = v;
        }
    }
}

// ---------------------------------------------------------------------------
// GEMM2: h2 = h1 @ W2^T + b2 (no relu), written to d_out, plus BN column
// partial sums (sum, sumsq) reduced in LDS then one global atomic per column.
// ---------------------------------------------------------------------------
__global__ __launch_bounds__(256) void gemm2_kernel(
    const float* __restrict__ h1, const float* __restrict__ W,
    const float* __restrict__ bias, float* __restrict__ out,
    float* __restrict__ statSum, float* __restrict__ statSqs, int N)
{
    __shared__ float sWT[HDIM * 129];
    __shared__ float sIn[TR * 132];
    __shared__ float sSum[HDIM];
    __shared__ float sSqs[HDIM];

    int t = threadIdx.x;
    int rb = blockIdx.x * TR;

    for (int i = t; i < HDIM * HDIM; i += 256) {
        int c = i >> 7, k = i & 127;
        sWT[k * 129 + c] = W[i];
    }
    for (int f = t; f < TR * (HDIM / 4); f += 256) {
        int r = f >> 5;
        int kg = (f & 31) * 4;
        int row = rb + r;
        float4 av;
        if (row < N) {
            av = *(const float4*)(h1 + (size_t)row * HDIM + kg);
        } else {
            av = make_float4(0.f, 0.f, 0.f, 0.f);
        }
        *(float4*)(&sIn[r * 132 + kg]) = av;
    }
    if (t < HDIM) { sSum[t] = 0.f; sSqs[t] = 0.f; }
    __syncthreads();

    int tx = t & 31, ty = t >> 5;
    int cb = tx * 4;
    float4 acc[4];
    #pragma unroll
    for (int i = 0; i < 4; i++) acc[i] = make_float4(0.f, 0.f, 0.f, 0.f);

    for (int k0 = 0; k0 < HDIM; k0 += 4) {
        float a[4][4];
        #pragma unroll
        for (int i = 0; i < 4; i++)
            *(float4*)a[i] = *(const float4*)(&sIn[(ty * 4 + i) * 132 + k0]);
        #pragma unroll
        for (int kk = 0; kk < 4; kk++) {
            const float* wrow = &sWT[(k0 + kk) * 129 + cb];
            float w0 = wrow[0], w1 = wrow[1], w2 = wrow[2], w3 = wrow[3];
            #pragma unroll
            for (int i = 0; i < 4; i++) {
                acc[i].x += a[i][kk] * w0;
                acc[i].y += a[i][kk] * w1;
                acc[i].z += a[i][kk] * w2;
                acc[i].w += a[i][kk] * w3;
            }
        }
    }

    float4 bb = *(const float4*)(bias + cb);
    float4 cs = make_float4(0.f, 0.f, 0.f, 0.f);
    float4 cq = make_float4(0.f, 0.f, 0.f, 0.f);
    #pragma unroll
    for (int i = 0; i < 4; i++) {
        int row = rb + ty * 4 + i;
        if (row < N) {
            float4 v;
            v.x = acc[i].x + bb.x;
            v.y = acc[i].y + bb.y;
            v.z = acc[i].z + bb.z;
            v.w = acc[i].w + bb.w;
            *(float4*)(out + (size_t)row * HDIM + cb) = v;
            cs.x += v.x; cs.y += v.y; cs.z += v.z; cs.w += v.w;
            cq.x += v.x * v.x; cq.y += v.y * v.y;
            cq.z += v.z * v.z; cq.w += v.w * v.w;
        }
    }
    atomicAdd(&sSum[cb + 0], cs.x);
    atomicAdd(&sSum[cb + 1], cs.y);
    atomicAdd(&sSum[cb + 2], cs.z);
    atomicAdd(&sSum[cb + 3], cs.w);
    atomicAdd(&sSqs[cb + 0], cq.x);
    atomicAdd(&sSqs[cb + 1], cq.y);
    atomicAdd(&sSqs[cb + 2], cq.z);
    atomicAdd(&sSqs[cb + 3], cq.w);
    __syncthreads();
    if (t < HDIM) {
        atomicAdd(&statSum[t], sSum[t]);
        atomicAdd(&statSqs[t], sSqs[t]);
    }
}

// ---------------------------------------------------------------------------
// BN prep: per-column scale/shift from accumulated stats
// ---------------------------------------------------------------------------
__global__ void bn_prep_kernel(
    const float* __restrict__ statSum, const float* __restrict__ statSqs,
    const float* __restrict__ gamma, const float* __restrict__ beta,
    float* __restrict__ scale, float* __restrict__ shift, int N)
{
    int c = threadIdx.x;
    float invN = 1.0f / (float)N;
    float mean = statSum[c] * invN;
    float var = statSqs[c] * invN - mean * mean;
    float sc = gamma[c] * rsqrtf(var + BN_EPS);
    scale[c] = sc;
    shift[c] = beta[c] - mean * sc;
}

// ---------------------------------------------------------------------------
// BN apply + final relu, in-place on d_out, float4-vectorized
// ---------------------------------------------------------------------------
__global__ __launch_bounds__(256) void bn_apply_kernel(
    float* __restrict__ out, const float* __restrict__ scale,
    const float* __restrict__ shift, long n4)
{
    long i = (long)blockIdx.x * blockDim.x + threadIdx.x;
    if (i >= n4) return;
    int cg = (int)(i & 31) * 4;
    float4 v = ((float4*)out)[i];
    float4 sc = *(const float4*)(scale + cg);
    float4 sh = *(const float4*)(shift + cg);
    v.x = fmaxf(v.x * sc.x + sh.x, 0.f);
    v.y = fmaxf(v.y * sc.y + sh.y, 0.f);
    v.z = fmaxf(v.z * sc.z + sh.z, 0.f);
    v.w = fmaxf(v.w * sc.w + sh.w, 0.f);
    ((float4*)out)[i] = v;
}

extern "C" void kernel_launch(void* const* d_in, const int* in_sizes, int n_in,
                              void* d_out, int out_size, void* d_ws, size_t ws_size,
                              hipStream_t stream) {
    const float* x     = (const float*)d_in[0];
    const int*   eidx  = (const int*)d_in[1];
    const float* eps   = (const float*)d_in[2];
    const float* W1    = (const float*)d_in[3];
    const float* b1    = (const float*)d_in[4];
    const float* W2    = (const float*)d_in[5];
    const float* b2    = (const float*)d_in[6];
    const float* gamma = (const float*)d_in[7];
    const float* beta  = (const float*)d_in[8];
    float* out = (float*)d_out;

    int N = in_sizes[0] / HDIM;
    int E = in_sizes[1] / 2;
    size_t NH = (size_t)N * HDIM;

    float* agg     = (float*)d_ws;          // N*H
    float* h1      = agg + NH;              // N*H
    float* statSum = h1 + NH;               // H
    float* statSqs = statSum + HDIM;        // H
    float* bnScale = statSqs + HDIM;        // H
    float* bnShift = bnScale + HDIM;        // H

    hipMemsetAsync(agg, 0, NH * sizeof(float), stream);
    hipMemsetAsync(statSum, 0, 2 * HDIM * sizeof(float), stream);

    long sthreads = (long)E * 32;
    scatter_kernel<<<(int)((sthreads + 255) / 256), 256, 0, stream>>>(x, eidx, agg, E);

    int gblocks = (N + TR - 1) / TR;
    gemm1_kernel<<<gblocks, 256, 0, stream>>>(agg, x, eps, W1, b1, h1, N);
    gemm2_kernel<<<gblocks, 256, 0, stream>>>(h1, W2, b2, out, statSum, statSqs, N);
    bn_prep_kernel<<<1, HDIM, 0, stream>>>(statSum, statSqs, gamma, beta, bnScale, bnShift, N);

    long n4 = (long)NH / 4;
    bn_apply_kernel<<<(int)((n4 + 255) / 256), 256, 0, stream>>>(out, bnScale, bnShift, n4);
}

// Round 2
// 415.813 us; speedup vs baseline: 3.1243x; 3.1243x over previous
//
#include <hip/hip_runtime.h>

#define HDIM 128
#define TR 32
#define BN_EPS 1e-5f

// ---------------------------------------------------------------------------
// Fallback atomic scatter (used only if ws_size too small for sort scratch)
// ---------------------------------------------------------------------------
__global__ __launch_bounds__(256) void scatter_kernel(
    const float* __restrict__ x, const int* __restrict__ eidx,
    float* __restrict__ agg, int E)
{
    long tid = (long)blockIdx.x * blockDim.x + threadIdx.x;
    int e = (int)(tid >> 5);
    if (e >= E) return;
    int g = (int)(tid & 31);
    int s = eidx[e];
    int t = eidx[E + e];
    const float4 v = *(const float4*)(x + (size_t)s * HDIM + g * 4);
    float* dst = agg + (size_t)t * HDIM + g * 4;
    atomicAdd(dst + 0, v.x);
    atomicAdd(dst + 1, v.y);
    atomicAdd(dst + 2, v.z);
    atomicAdd(dst + 3, v.w);
}

__global__ __launch_bounds__(256) void addself_kernel(
    const float* __restrict__ x, const float* __restrict__ eps,
    float* __restrict__ agg, long n4)
{
    long i = (long)blockIdx.x * blockDim.x + threadIdx.x;
    if (i >= n4) return;
    float coef = 1.0f + eps[0];
    float4 a = ((float4*)agg)[i];
    float4 xv = ((const float4*)x)[i];
    a.x += coef * xv.x; a.y += coef * xv.y;
    a.z += coef * xv.z; a.w += coef * xv.w;
    ((float4*)agg)[i] = a;
}

// ---------------------------------------------------------------------------
// Counting-sort path
// ---------------------------------------------------------------------------
__global__ __launch_bounds__(256) void hist_kernel(
    const int* __restrict__ eidx, int* __restrict__ hist, int E)
{
    int i = blockIdx.x * blockDim.x + threadIdx.x;
    int stride = gridDim.x * blockDim.x;
    for (int e = i; e < E; e += stride) {
        atomicAdd(&hist[eidx[E + e]], 1);
    }
}

// single block, 1024 threads: exclusive scan of hist[0..N) -> offsets, cursor
__global__ __launch_bounds__(1024) void scan_kernel(
    const int* __restrict__ hist, int* __restrict__ offsets,
    int* __restrict__ cursor, int N)
{
    __shared__ int ssum[1024];
    int t = threadIdx.x;
    int chunk = (N + 1023) / 1024;
    int lo = t * chunk;
    int hi = lo + chunk; if (hi > N) hi = N;
    int s = 0;
    for (int i = lo; i < hi; i++) s += hist[i];
    ssum[t] = s;
    __syncthreads();
    // Hillis-Steele inclusive scan
    for (int off = 1; off < 1024; off <<= 1) {
        int v = ssum[t];
        int add = (t >= off) ? ssum[t - off] : 0;
        __syncthreads();
        ssum[t] = v + add;
        __syncthreads();
    }
    int excl = ssum[t] - s;
    for (int i = lo; i < hi; i++) {
        offsets[i] = excl;
        cursor[i] = excl;
        excl += hist[i];
    }
    if (t == 1023) offsets[N] = ssum[1023];
}

__global__ __launch_bounds__(256) void reorder_kernel(
    const int* __restrict__ eidx, int* __restrict__ cursor,
    int* __restrict__ srcSorted, int E)
{
    int i = blockIdx.x * blockDim.x + threadIdx.x;
    int stride = gridDim.x * blockDim.x;
    for (int e = i; e < E; e += stride) {
        int s = eidx[e];
        int t = eidx[E + e];
        int pos = atomicAdd(&cursor[t], 1);
        srcSorted[pos] = s;
    }
}

// 32 lanes per row, 8 rows per block. agg[row] = coef*x[row] + sum x[src]
__global__ __launch_bounds__(256) void aggregate_kernel(
    const float* __restrict__ x, const int* __restrict__ offsets,
    const int* __restrict__ srcSorted, const float* __restrict__ eps,
    float* __restrict__ agg, int N)
{
    int t = threadIdx.x;
    int tx = t & 31, ty = t >> 5;
    int row = blockIdx.x * 8 + ty;
    if (row >= N) return;
    float coef = 1.0f + eps[0];
    int col = tx * 4;
    float4 xv = *(const float4*)(x + (size_t)row * HDIM + col);
    float4 acc;
    acc.x = coef * xv.x; acc.y = coef * xv.y;
    acc.z = coef * xv.z; acc.w = coef * xv.w;
    int beg = offsets[row], end = offsets[row + 1];
    for (int e = beg; e < end; e++) {
        int s = srcSorted[e];
        float4 v = *(const float4*)(x + (size_t)s * HDIM + col);
        acc.x += v.x; acc.y += v.y; acc.z += v.z; acc.w += v.w;
    }
    *(float4*)(agg + (size_t)row * HDIM + col) = acc;
}

// ---------------------------------------------------------------------------
// GEMM1: h1 = relu(agg @ W1^T + b1)
// ---------------------------------------------------------------------------
__global__ __launch_bounds__(256) void gemm1_kernel(
    const float* __restrict__ agg, const float* __restrict__ W,
    const float* __restrict__ bias, float* __restrict__ out, int N)
{
    __shared__ float sWT[HDIM * 129];   // sWT[k*129+c] = W[c*128+k]
    __shared__ float sIn[TR * 132];

    int t = threadIdx.x;
    int rb = blockIdx.x * TR;

    for (int i = t; i < HDIM * HDIM; i += 256) {
        int c = i >> 7, k = i & 127;
        sWT[k * 129 + c] = W[i];
    }
    for (int f = t; f < TR * (HDIM / 4); f += 256) {
        int r = f >> 5;
        int kg = (f & 31) * 4;
        int row = rb + r;
        float4 av;
        if (row < N) {
            av = *(const float4*)(agg + (size_t)row * HDIM + kg);
        } else {
            av = make_float4(0.f, 0.f, 0.f, 0.f);
        }
        *(float4*)(&sIn[r * 132 + kg]) = av;
    }
    __syncthreads();

    int tx = t & 31, ty = t >> 5;
    int cb = tx * 4;
    float4 acc[4];
    #pragma unroll
    for (int i = 0; i < 4; i++) acc[i] = make_float4(0.f, 0.f, 0.f, 0.f);

    for (int k0 = 0; k0 < HDIM; k0 += 4) {
        float a[4][4];
        #pragma unroll
        for (int i = 0; i < 4; i++)
            *(float4*)a[i] = *(const float4*)(&sIn[(ty * 4 + i) * 132 + k0]);
        #pragma unroll
        for (int kk = 0; kk < 4; kk++) {
            const float* wrow = &sWT[(k0 + kk) * 129 + cb];
            float w0 = wrow[0], w1 = wrow[1], w2 = wrow[2], w3 = wrow[3];
            #pragma unroll
            for (int i = 0; i < 4; i++) {
                acc[i].x += a[i][kk] * w0;
                acc[i].y += a[i][kk] * w1;
                acc[i].z += a[i][kk] * w2;
                acc[i].w += a[i][kk] * w3;
            }
        }
    }

    float4 bb = *(const float4*)(bias + cb);
    #pragma unroll
    for (int i = 0; i < 4; i++) {
        int row = rb + ty * 4 + i;
        if (row < N) {
            float4 v;
            v.x = fmaxf(acc[i].x + bb.x, 0.f);
            v.y = fmaxf(acc[i].y + bb.y, 0.f);
            v.z = fmaxf(acc[i].z + bb.z, 0.f);
            v.w = fmaxf(acc[i].w + bb.w, 0.f);
            *(float4*)(out + (size_t)row * HDIM + cb) = v;
        }
    }
}

// ---------------------------------------------------------------------------
// GEMM2: d_out = h1 @ W2^T + b2, + BN column stats via LDS + global atomics
// ---------------------------------------------------------------------------
__global__ __launch_bounds__(256) void gemm2_kernel(
    const float* __restrict__ h1, const float* __restrict__ W,
    const float* __restrict__ bias, float* __restrict__ out,
    float* __restrict__ statSum, float* __restrict__ statSqs, int N)
{
    __shared__ float sWT[HDIM * 129];
    __shared__ float sIn[TR * 132];
    __shared__ float sSum[HDIM];
    __shared__ float sSqs[HDIM];

    int t = threadIdx.x;
    int rb = blockIdx.x * TR;

    for (int i = t; i < HDIM * HDIM; i += 256) {
        int c = i >> 7, k = i & 127;
        sWT[k * 129 + c] = W[i];
    }
    for (int f = t; f < TR * (HDIM / 4); f += 256) {
        int r = f >> 5;
        int kg = (f & 31) * 4;
        int row = rb + r;
        float4 av;
        if (row < N) {
            av = *(const float4*)(h1 + (size_t)row * HDIM + kg);
        } else {
            av = make_float4(0.f, 0.f, 0.f, 0.f);
        }
        *(float4*)(&sIn[r * 132 + kg]) = av;
    }
    if (t < HDIM) { sSum[t] = 0.f; sSqs[t] = 0.f; }
    __syncthreads();

    int tx = t & 31, ty = t >> 5;
    int cb = tx * 4;
    float4 acc[4];
    #pragma unroll
    for (int i = 0; i < 4; i++) acc[i] = make_float4(0.f, 0.f, 0.f, 0.f);

    for (int k0 = 0; k0 < HDIM; k0 += 4) {
        float a[4][4];
        #pragma unroll
        for (int i = 0; i < 4; i++)
            *(float4*)a[i] = *(const float4*)(&sIn[(ty * 4 + i) * 132 + k0]);
        #pragma unroll
        for (int kk = 0; kk < 4; kk++) {
            const float* wrow = &sWT[(k0 + kk) * 129 + cb];
            float w0 = wrow[0], w1 = wrow[1], w2 = wrow[2], w3 = wrow[3];
            #pragma unroll
            for (int i = 0; i < 4; i++) {
                acc[i].x += a[i][kk] * w0;
                acc[i].y += a[i][kk] * w1;
                acc[i].z += a[i][kk] * w2;
                acc[i].w += a[i][kk] * w3;
            }
        }
    }

    float4 bb = *(const float4*)(bias + cb);
    float4 cs = make_float4(0.f, 0.f, 0.f, 0.f);
    float4 cq = make_float4(0.f, 0.f, 0.f, 0.f);
    #pragma unroll
    for (int i = 0; i < 4; i++) {
        int row = rb + ty * 4 + i;
        if (row < N) {
            float4 v;
            v.x = acc[i].x + bb.x;
            v.y = acc[i].y + bb.y;
            v.z = acc[i].z + bb.z;
            v.w = acc[i].w + bb.w;
            *(float4*)(out + (size_t)row * HDIM + cb) = v;
            cs.x += v.x; cs.y += v.y; cs.z += v.z; cs.w += v.w;
            cq.x += v.x * v.x; cq.y += v.y * v.y;
            cq.z += v.z * v.z; cq.w += v.w * v.w;
        }
    }
    atomicAdd(&sSum[cb + 0], cs.x);
    atomicAdd(&sSum[cb + 1], cs.y);
    atomicAdd(&sSum[cb + 2], cs.z);
    atomicAdd(&sSum[cb + 3], cs.w);
    atomicAdd(&sSqs[cb + 0], cq.x);
    atomicAdd(&sSqs[cb + 1], cq.y);
    atomicAdd(&sSqs[cb + 2], cq.z);
    atomicAdd(&sSqs[cb + 3], cq.w);
    __syncthreads();
    if (t < HDIM) {
        atomicAdd(&statSum[t], sSum[t]);
        atomicAdd(&statSqs[t], sSqs[t]);
    }
}

__global__ void bn_prep_kernel(
    const float* __restrict__ statSum, const float* __restrict__ statSqs,
    const float* __restrict__ gamma, const float* __restrict__ beta,
    float* __restrict__ scale, float* __restrict__ shift, int N)
{
    int c = threadIdx.x;
    float invN = 1.0f / (float)N;
    float mean = statSum[c] * invN;
    float var = statSqs[c] * invN - mean * mean;
    float sc = gamma[c] * rsqrtf(var + BN_EPS);
    scale[c] = sc;
    shift[c] = beta[c] - mean * sc;
}

__global__ __launch_bounds__(256) void bn_apply_kernel(
    float* __restrict__ out, const float* __restrict__ scale,
    const float* __restrict__ shift, long n4)
{
    long i = (long)blockIdx.x * blockDim.x + threadIdx.x;
    if (i >= n4) return;
    int cg = (int)(i & 31) * 4;
    float4 v = ((float4*)out)[i];
    float4 sc = *(const float4*)(scale + cg);
    float4 sh = *(const float4*)(shift + cg);
    v.x = fmaxf(v.x * sc.x + sh.x, 0.f);
    v.y = fmaxf(v.y * sc.y + sh.y, 0.f);
    v.z = fmaxf(v.z * sc.z + sh.z, 0.f);
    v.w = fmaxf(v.w * sc.w + sh.w, 0.f);
    ((float4*)out)[i] = v;
}

extern "C" void kernel_launch(void* const* d_in, const int* in_sizes, int n_in,
                              void* d_out, int out_size, void* d_ws, size_t ws_size,
                              hipStream_t stream) {
    const float* x     = (const float*)d_in[0];
    const int*   eidx  = (const int*)d_in[1];
    const float* eps   = (const float*)d_in[2];
    const float* W1    = (const float*)d_in[3];
    const float* b1    = (const float*)d_in[4];
    const float* W2    = (const float*)d_in[5];
    const float* b2    = (const float*)d_in[6];
    const float* gamma = (const float*)d_in[7];
    const float* beta  = (const float*)d_in[8];
    float* out = (float*)d_out;

    int N = in_sizes[0] / HDIM;
    int E = in_sizes[1] / 2;
    size_t NH = (size_t)N * HDIM;

    float* agg     = (float*)d_ws;          // N*H floats
    float* h1      = agg + NH;              // N*H floats
    float* statSum = h1 + NH;               // H
    float* statSqs = statSum + HDIM;        // H
    float* bnScale = statSqs + HDIM;        // H
    float* bnShift = bnScale + HDIM;        // H
    int*   hist    = (int*)(bnShift + HDIM);        // N
    int*   offsets = hist + N;                      // N+1
    int*   cursor  = offsets + N + 1;               // N
    int*   srcSorted = cursor + N;                  // E

    size_t needed = (2 * NH + 4 * HDIM) * sizeof(float)
                  + (size_t)(3 * N + 1 + E) * sizeof(int);

    hipMemsetAsync(statSum, 0, 2 * HDIM * sizeof(float), stream);

    if (ws_size >= needed) {
        // ---- counting-sort path: no fp32 atomics ----
        hipMemsetAsync(hist, 0, (size_t)N * sizeof(int), stream);
        hist_kernel<<<512, 256, 0, stream>>>(eidx, hist, E);
        scan_kernel<<<1, 1024, 0, stream>>>(hist, offsets, cursor, N);
        reorder_kernel<<<512, 256, 0, stream>>>(eidx, cursor, srcSorted, E);
        aggregate_kernel<<<(N + 7) / 8, 256, 0, stream>>>(x, offsets, srcSorted, eps, agg, N);
    } else {
        // ---- fallback: atomic scatter ----
        hipMemsetAsync(agg, 0, NH * sizeof(float), stream);
        long sthreads = (long)E * 32;
        scatter_kernel<<<(int)((sthreads + 255) / 256), 256, 0, stream>>>(x, eidx, agg, E);
        long n4 = (long)NH / 4;
        addself_kernel<<<(int)((n4 + 255) / 256), 256, 0, stream>>>(x, eps, agg, n4);
    }

    int gblocks = (N + TR - 1) / TR;
    gemm1_kernel<<<gblocks, 256, 0, stream>>>(agg, W1, b1, h1, N);
    gemm2_kernel<<<gblocks, 256, 0, stream>>>(h1, W2, b2, out, statSum, statSqs, N);
    bn_prep_kernel<<<1, HDIM, 0, stream>>>(statSum, statSqs, gamma, beta, bnScale, bnShift, N);

    long n4 = (long)NH / 4;
    bn_apply_kernel<<<(int)((n4 + 255) / 256), 256, 0, stream>>>(out, bnScale, bnShift, n4);
}

// Round 3
// 332.614 us; speedup vs baseline: 3.9058x; 1.2501x over previous
//
#include <hip/hip_runtime.h>

#define HDIM 128
#define TR 32
#define BN_EPS 1e-5f
#define SCAN_BINS 1024   // bins per block in the two-level scan

// ---------------------------------------------------------------------------
// Fallback atomic scatter (used only if ws_size too small for sort scratch)
// ---------------------------------------------------------------------------
__global__ __launch_bounds__(256) void scatter_kernel(
    const float* __restrict__ x, const int* __restrict__ eidx,
    float* __restrict__ agg, int E)
{
    long tid = (long)blockIdx.x * blockDim.x + threadIdx.x;
    int e = (int)(tid >> 5);
    if (e >= E) return;
    int g = (int)(tid & 31);
    int s = eidx[e];
    int t = eidx[E + e];
    const float4 v = *(const float4*)(x + (size_t)s * HDIM + g * 4);
    float* dst = agg + (size_t)t * HDIM + g * 4;
    atomicAdd(dst + 0, v.x);
    atomicAdd(dst + 1, v.y);
    atomicAdd(dst + 2, v.z);
    atomicAdd(dst + 3, v.w);
}

__global__ __launch_bounds__(256) void addself_kernel(
    const float* __restrict__ x, const float* __restrict__ eps,
    float* __restrict__ agg, long n4)
{
    long i = (long)blockIdx.x * blockDim.x + threadIdx.x;
    if (i >= n4) return;
    float coef = 1.0f + eps[0];
    float4 a = ((float4*)agg)[i];
    float4 xv = ((const float4*)x)[i];
    a.x += coef * xv.x; a.y += coef * xv.y;
    a.z += coef * xv.z; a.w += coef * xv.w;
    ((float4*)agg)[i] = a;
}

// ---------------------------------------------------------------------------
// Counting-sort path
// ---------------------------------------------------------------------------
__global__ __launch_bounds__(256) void hist_kernel(
    const int* __restrict__ eidx, int* __restrict__ hist, int E)
{
    int i = blockIdx.x * blockDim.x + threadIdx.x;
    int stride = gridDim.x * blockDim.x;
    for (int e = i; e < E; e += stride) {
        atomicAdd(&hist[eidx[E + e]], 1);
    }
}

// Two-level scan, level 1: each block scans SCAN_BINS bins.
// Writes block-local exclusive offsets and the block total.
__global__ __launch_bounds__(256) void block_scan_kernel(
    const int* __restrict__ hist, int* __restrict__ offsets,
    int* __restrict__ blockSums, int N)
{
    __shared__ int ts[256];
    int b = blockIdx.x, t = threadIdx.x;
    int base = b * SCAN_BINS + t * 4;
    int4 h = make_int4(0, 0, 0, 0);
    if (base + 3 < N) {
        h = *(const int4*)(hist + base);
    } else {
        if (base + 0 < N) h.x = hist[base + 0];
        if (base + 1 < N) h.y = hist[base + 1];
        if (base + 2 < N) h.z = hist[base + 2];
    }
    int s = h.x + h.y + h.z + h.w;
    ts[t] = s;
    __syncthreads();
    for (int off = 1; off < 256; off <<= 1) {
        int v = ts[t];
        int add = (t >= off) ? ts[t - off] : 0;
        __syncthreads();
        ts[t] = v + add;
        __syncthreads();
    }
    int excl = ts[t] - s;
    int4 o;
    o.x = excl;
    o.y = o.x + h.x;
    o.z = o.y + h.y;
    o.w = o.z + h.z;
    if (base + 3 < N) {
        *(int4*)(offsets + base) = o;
    } else {
        if (base + 0 < N) offsets[base + 0] = o.x;
        if (base + 1 < N) offsets[base + 1] = o.y;
        if (base + 2 < N) offsets[base + 2] = o.z;
    }
    if (t == 255) blockSums[b] = ts[255];
}

// Two-level scan, level 2: each block shfl-scans blockSums (NB<=64) in wave 0,
// adds its exclusive prefix to its offsets chunk, mirrors into cursor.
__global__ __launch_bounds__(256) void scan_finalize_kernel(
    const int* __restrict__ blockSums, int* __restrict__ offsets,
    int* __restrict__ cursor, int N, int NB)
{
    __shared__ int sPrefix;
    int b = blockIdx.x, t = threadIdx.x;
    if (t < 64) {
        int v = (t < NB) ? blockSums[t] : 0;
        #pragma unroll
        for (int off = 1; off < 64; off <<= 1) {
            int u = __shfl_up(v, off, 64);
            if (t >= off) v += u;
        }
        int pre = __shfl(v, (b == 0) ? 0 : b - 1, 64);
        if (b == 0) pre = 0;
        int total = __shfl(v, NB - 1, 64);
        if (t == 0) {
            sPrefix = pre;
            if (b == 0) offsets[N] = total;
        }
    }
    __syncthreads();
    int prefix = sPrefix;
    int base = b * SCAN_BINS + t * 4;
    if (base + 3 < N) {
        int4 o = *(int4*)(offsets + base);
        o.x += prefix; o.y += prefix; o.z += prefix; o.w += prefix;
        *(int4*)(offsets + base) = o;
        *(int4*)(cursor + base) = o;
    } else {
        for (int j = 0; j < 4; j++) {
            int i = base + j;
            if (i < N) {
                int v = offsets[i] + prefix;
                offsets[i] = v;
                cursor[i] = v;
            }
        }
    }
}

// Fallback single-block scan (only if NB > 64)
__global__ __launch_bounds__(1024) void scan_kernel(
    const int* __restrict__ hist, int* __restrict__ offsets,
    int* __restrict__ cursor, int N)
{
    __shared__ int ssum[1024];
    int t = threadIdx.x;
    int chunk = (N + 1023) / 1024;
    int lo = t * chunk;
    int hi = lo + chunk; if (hi > N) hi = N;
    int s = 0;
    for (int i = lo; i < hi; i++) s += hist[i];
    ssum[t] = s;
    __syncthreads();
    for (int off = 1; off < 1024; off <<= 1) {
        int v = ssum[t];
        int add = (t >= off) ? ssum[t - off] : 0;
        __syncthreads();
        ssum[t] = v + add;
        __syncthreads();
    }
    int excl = ssum[t] - s;
    for (int i = lo; i < hi; i++) {
        offsets[i] = excl;
        cursor[i] = excl;
        excl += hist[i];
    }
    if (t == 1023) offsets[N] = ssum[1023];
}

__global__ __launch_bounds__(256) void reorder_kernel(
    const int* __restrict__ eidx, int* __restrict__ cursor,
    int* __restrict__ srcSorted, int E)
{
    int i = blockIdx.x * blockDim.x + threadIdx.x;
    int stride = gridDim.x * blockDim.x;
    for (int e = i; e < E; e += stride) {
        int s = eidx[e];
        int t = eidx[E + e];
        int pos = atomicAdd(&cursor[t], 1);
        srcSorted[pos] = s;
    }
}

// 32 lanes per row, 8 rows per block. agg[row] = coef*x[row] + sum x[src]
__global__ __launch_bounds__(256) void aggregate_kernel(
    const float* __restrict__ x, const int* __restrict__ offsets,
    const int* __restrict__ srcSorted, const float* __restrict__ eps,
    float* __restrict__ agg, int N)
{
    int t = threadIdx.x;
    int tx = t & 31, ty = t >> 5;
    int row = blockIdx.x * 8 + ty;
    if (row >= N) return;
    float coef = 1.0f + eps[0];
    int col = tx * 4;
    float4 xv = *(const float4*)(x + (size_t)row * HDIM + col);
    float4 acc;
    acc.x = coef * xv.x; acc.y = coef * xv.y;
    acc.z = coef * xv.z; acc.w = coef * xv.w;
    int beg = offsets[row], end = offsets[row + 1];
    for (int e = beg; e < end; e++) {
        int s = srcSorted[e];
        float4 v = *(const float4*)(x + (size_t)s * HDIM + col);
        acc.x += v.x; acc.y += v.y; acc.z += v.z; acc.w += v.w;
    }
    *(float4*)(agg + (size_t)row * HDIM + col) = acc;
}

// ---------------------------------------------------------------------------
// GEMM1: h1 = relu(agg @ W1^T + b1)
// ---------------------------------------------------------------------------
__global__ __launch_bounds__(256) void gemm1_kernel(
    const float* __restrict__ agg, const float* __restrict__ W,
    const float* __restrict__ bias, float* __restrict__ out, int N)
{
    __shared__ float sWT[HDIM * 129];   // sWT[k*129+c] = W[c*128+k]
    __shared__ float sIn[TR * 132];

    int t = threadIdx.x;
    int rb = blockIdx.x * TR;

    for (int i = t; i < HDIM * HDIM; i += 256) {
        int c = i >> 7, k = i & 127;
        sWT[k * 129 + c] = W[i];
    }
    for (int f = t; f < TR * (HDIM / 4); f += 256) {
        int r = f >> 5;
        int kg = (f & 31) * 4;
        int row = rb + r;
        float4 av;
        if (row < N) {
            av = *(const float4*)(agg + (size_t)row * HDIM + kg);
        } else {
            av = make_float4(0.f, 0.f, 0.f, 0.f);
        }
        *(float4*)(&sIn[r * 132 + kg]) = av;
    }
    __syncthreads();

    int tx = t & 31, ty = t >> 5;
    int cb = tx * 4;
    float4 acc[4];
    #pragma unroll
    for (int i = 0; i < 4; i++) acc[i] = make_float4(0.f, 0.f, 0.f, 0.f);

    for (int k0 = 0; k0 < HDIM; k0 += 4) {
        float a[4][4];
        #pragma unroll
        for (int i = 0; i < 4; i++)
            *(float4*)a[i] = *(const float4*)(&sIn[(ty * 4 + i) * 132 + k0]);
        #pragma unroll
        for (int kk = 0; kk < 4; kk++) {
            const float* wrow = &sWT[(k0 + kk) * 129 + cb];
            float w0 = wrow[0], w1 = wrow[1], w2 = wrow[2], w3 = wrow[3];
            #pragma unroll
            for (int i = 0; i < 4; i++) {
                acc[i].x += a[i][kk] * w0;
                acc[i].y += a[i][kk] * w1;
                acc[i].z += a[i][kk] * w2;
                acc[i].w += a[i][kk] * w3;
            }
        }
    }

    float4 bb = *(const float4*)(bias + cb);
    #pragma unroll
    for (int i = 0; i < 4; i++) {
        int row = rb + ty * 4 + i;
        if (row < N) {
            float4 v;
            v.x = fmaxf(acc[i].x + bb.x, 0.f);
            v.y = fmaxf(acc[i].y + bb.y, 0.f);
            v.z = fmaxf(acc[i].z + bb.z, 0.f);
            v.w = fmaxf(acc[i].w + bb.w, 0.f);
            *(float4*)(out + (size_t)row * HDIM + cb) = v;
        }
    }
}

// ---------------------------------------------------------------------------
// GEMM2: d_out = h1 @ W2^T + b2, + BN column stats via LDS + global atomics
// ---------------------------------------------------------------------------
__global__ __launch_bounds__(256) void gemm2_kernel(
    const float* __restrict__ h1, const float* __restrict__ W,
    const float* __restrict__ bias, float* __restrict__ out,
    float* __restrict__ statSum, float* __restrict__ statSqs, int N)
{
    __shared__ float sWT[HDIM * 129];
    __shared__ float sIn[TR * 132];
    __shared__ float sSum[HDIM];
    __shared__ float sSqs[HDIM];

    int t = threadIdx.x;
    int rb = blockIdx.x * TR;

    for (int i = t; i < HDIM * HDIM; i += 256) {
        int c = i >> 7, k = i & 127;
        sWT[k * 129 + c] = W[i];
    }
    for (int f = t; f < TR * (HDIM / 4); f += 256) {
        int r = f >> 5;
        int kg = (f & 31) * 4;
        int row = rb + r;
        float4 av;
        if (row < N) {
            av = *(const float4*)(h1 + (size_t)row * HDIM + kg);
        } else {
            av = make_float4(0.f, 0.f, 0.f, 0.f);
        }
        *(float4*)(&sIn[r * 132 + kg]) = av;
    }
    if (t < HDIM) { sSum[t] = 0.f; sSqs[t] = 0.f; }
    __syncthreads();

    int tx = t & 31, ty = t >> 5;
    int cb = tx * 4;
    float4 acc[4];
    #pragma unroll
    for (int i = 0; i < 4; i++) acc[i] = make_float4(0.f, 0.f, 0.f, 0.f);

    for (int k0 = 0; k0 < HDIM; k0 += 4) {
        float a[4][4];
        #pragma unroll
        for (int i = 0; i < 4; i++)
            *(float4*)a[i] = *(const float4*)(&sIn[(ty * 4 + i) * 132 + k0]);
        #pragma unroll
        for (int kk = 0; kk < 4; kk++) {
            const float* wrow = &sWT[(k0 + kk) * 129 + cb];
            float w0 = wrow[0], w1 = wrow[1], w2 = wrow[2], w3 = wrow[3];
            #pragma unroll
            for (int i = 0; i < 4; i++) {
                acc[i].x += a[i][kk] * w0;
                acc[i].y += a[i][kk] * w1;
                acc[i].z += a[i][kk] * w2;
                acc[i].w += a[i][kk] * w3;
            }
        }
    }

    float4 bb = *(const float4*)(bias + cb);
    float4 cs = make_float4(0.f, 0.f, 0.f, 0.f);
    float4 cq = make_float4(0.f, 0.f, 0.f, 0.f);
    #pragma unroll
    for (int i = 0; i < 4; i++) {
        int row = rb + ty * 4 + i;
        if (row < N) {
            float4 v;
            v.x = acc[i].x + bb.x;
            v.y = acc[i].y + bb.y;
            v.z = acc[i].z + bb.z;
            v.w = acc[i].w + bb.w;
            *(float4*)(out + (size_t)row * HDIM + cb) = v;
            cs.x += v.x; cs.y += v.y; cs.z += v.z; cs.w += v.w;
            cq.x += v.x * v.x; cq.y += v.y * v.y;
            cq.z += v.z * v.z; cq.w += v.w * v.w;
        }
    }
    atomicAdd(&sSum[cb + 0], cs.x);
    atomicAdd(&sSum[cb + 1], cs.y);
    atomicAdd(&sSum[cb + 2], cs.z);
    atomicAdd(&sSum[cb + 3], cs.w);
    atomicAdd(&sSqs[cb + 0], cq.x);
    atomicAdd(&sSqs[cb + 1], cq.y);
    atomicAdd(&sSqs[cb + 2], cq.z);
    atomicAdd(&sSqs[cb + 3], cq.w);
    __syncthreads();
    if (t < HDIM) {
        atomicAdd(&statSum[t], sSum[t]);
        atomicAdd(&statSqs[t], sSqs[t]);
    }
}

__global__ void bn_prep_kernel(
    const float* __restrict__ statSum, const float* __restrict__ statSqs,
    const float* __restrict__ gamma, const float* __restrict__ beta,
    float* __restrict__ scale, float* __restrict__ shift, int N)
{
    int c = threadIdx.x;
    float invN = 1.0f / (float)N;
    float mean = statSum[c] * invN;
    float var = statSqs[c] * invN - mean * mean;
    float sc = gamma[c] * rsqrtf(var + BN_EPS);
    scale[c] = sc;
    shift[c] = beta[c] - mean * sc;
}

__global__ __launch_bounds__(256) void bn_apply_kernel(
    float* __restrict__ out, const float* __restrict__ scale,
    const float* __restrict__ shift, long n4)
{
    long i = (long)blockIdx.x * blockDim.x + threadIdx.x;
    if (i >= n4) return;
    int cg = (int)(i & 31) * 4;
    float4 v = ((float4*)out)[i];
    float4 sc = *(const float4*)(scale + cg);
    float4 sh = *(const float4*)(shift + cg);
    v.x = fmaxf(v.x * sc.x + sh.x, 0.f);
    v.y = fmaxf(v.y * sc.y + sh.y, 0.f);
    v.z = fmaxf(v.z * sc.z + sh.z, 0.f);
    v.w = fmaxf(v.w * sc.w + sh.w, 0.f);
    ((float4*)out)[i] = v;
}

extern "C" void kernel_launch(void* const* d_in, const int* in_sizes, int n_in,
                              void* d_out, int out_size, void* d_ws, size_t ws_size,
                              hipStream_t stream) {
    const float* x     = (const float*)d_in[0];
    const int*   eidx  = (const int*)d_in[1];
    const float* eps   = (const float*)d_in[2];
    const float* W1    = (const float*)d_in[3];
    const float* b1    = (const float*)d_in[4];
    const float* W2    = (const float*)d_in[5];
    const float* b2    = (const float*)d_in[6];
    const float* gamma = (const float*)d_in[7];
    const float* beta  = (const float*)d_in[8];
    float* out = (float*)d_out;

    int N = in_sizes[0] / HDIM;
    int E = in_sizes[1] / 2;
    size_t NH = (size_t)N * HDIM;
    int NB = (N + SCAN_BINS - 1) / SCAN_BINS;  // scan level-1 blocks
    int NpadOff = (N + 1 + 3) & ~3;            // offsets slot padded to int4

    float* agg     = (float*)d_ws;          // N*H floats
    float* h1      = agg + NH;              // N*H floats
    float* statSum = h1 + NH;               // H
    float* statSqs = statSum + HDIM;        // H
    float* bnScale = statSqs + HDIM;        // H
    float* bnShift = bnScale + HDIM;        // H
    int*   hist    = (int*)(bnShift + HDIM);        // N
    int*   offsets = hist + N;                      // NpadOff (holds N+1)
    int*   cursor  = offsets + NpadOff;             // N
    int*   srcSorted = cursor + N;                  // E
    int*   blockSums = srcSorted + E;               // NB

    size_t needed = (2 * NH + 4 * HDIM) * sizeof(float)
                  + (size_t)(2 * N + NpadOff + E + NB) * sizeof(int);

    hipMemsetAsync(statSum, 0, 2 * HDIM * sizeof(float), stream);

    if (ws_size >= needed) {
        // ---- counting-sort path: no fp32 atomics ----
        hipMemsetAsync(hist, 0, (size_t)N * sizeof(int), stream);
        hist_kernel<<<512, 256, 0, stream>>>(eidx, hist, E);
        if (NB <= 64) {
            block_scan_kernel<<<NB, 256, 0, stream>>>(hist, offsets, blockSums, N);
            scan_finalize_kernel<<<NB, 256, 0, stream>>>(blockSums, offsets, cursor, N, NB);
        } else {
            scan_kernel<<<1, 1024, 0, stream>>>(hist, offsets, cursor, N);
        }
        reorder_kernel<<<512, 256, 0, stream>>>(eidx, cursor, srcSorted, E);
        aggregate_kernel<<<(N + 7) / 8, 256, 0, stream>>>(x, offsets, srcSorted, eps, agg, N);
    } else {
        // ---- fallback: atomic scatter ----
        hipMemsetAsync(agg, 0, NH * sizeof(float), stream);
        long sthreads = (long)E * 32;
        scatter_kernel<<<(int)((sthreads + 255) / 256), 256, 0, stream>>>(x, eidx, agg, E);
        long n4 = (long)NH / 4;
        addself_kernel<<<(int)((n4 + 255) / 256), 256, 0, stream>>>(x, eps, agg, n4);
    }

    int gblocks = (N + TR - 1) / TR;
    gemm1_kernel<<<gblocks, 256, 0, stream>>>(agg, W1, b1, h1, N);
    gemm2_kernel<<<gblocks, 256, 0, stream>>>(h1, W2, b2, out, statSum, statSqs, N);
    bn_prep_kernel<<<1, HDIM, 0, stream>>>(statSum, statSqs, gamma, beta, bnScale, bnShift, N);

    long n4 = (long)NH / 4;
    bn_apply_kernel<<<(int)((n4 + 255) / 256), 256, 0, stream>>>(out, bnScale, bnShift, n4);
}

// Round 4
// 270.875 us; speedup vs baseline: 4.7960x; 1.2279x over previous
//
#include <hip/hip_runtime.h>

#define HDIM 128
#define BN_EPS 1e-5f
#define SCAN_BINS 1024

typedef short short8 __attribute__((ext_vector_type(8)));
typedef float floatx4 __attribute__((ext_vector_type(4)));

__device__ __forceinline__ unsigned short f2b(float f) {
    union { float f; unsigned u; } v; v.f = f;
    unsigned r = v.u + 0x7FFFu + ((v.u >> 16) & 1u);   // RNE
    return (unsigned short)(r >> 16);
}

// ---------------------------------------------------------------------------
// Converters: weights and x to bf16
// ---------------------------------------------------------------------------
__global__ __launch_bounds__(256) void convert_w_kernel(
    const float* __restrict__ W1, const float* __restrict__ W2,
    unsigned short* __restrict__ W1B, unsigned short* __restrict__ W2B)
{
    int i = blockIdx.x * 256 + threadIdx.x;   // 16384 total
    W1B[i] = f2b(W1[i]);
    W2B[i] = f2b(W2[i]);
}

__global__ __launch_bounds__(256) void convert_x_kernel(
    const float* __restrict__ x, unsigned short* __restrict__ xB, long n4)
{
    long i = (long)blockIdx.x * 256 + threadIdx.x;
    if (i >= n4) return;
    float4 v = ((const float4*)x)[i];
    ushort4 o;
    o.x = f2b(v.x); o.y = f2b(v.y); o.z = f2b(v.z); o.w = f2b(v.w);
    ((ushort4*)xB)[i] = o;
}

// ---------------------------------------------------------------------------
// Counting-sort path
// ---------------------------------------------------------------------------
__global__ __launch_bounds__(256) void hist_kernel(
    const int* __restrict__ eidx, int* __restrict__ hist, int E)
{
    int i = blockIdx.x * blockDim.x + threadIdx.x;
    int stride = gridDim.x * blockDim.x;
    for (int e = i; e < E; e += stride) {
        atomicAdd(&hist[eidx[E + e]], 1);
    }
}

__global__ __launch_bounds__(256) void block_scan_kernel(
    const int* __restrict__ hist, int* __restrict__ offsets,
    int* __restrict__ blockSums, int N)
{
    __shared__ int ts[256];
    int b = blockIdx.x, t = threadIdx.x;
    int base = b * SCAN_BINS + t * 4;
    int4 h = make_int4(0, 0, 0, 0);
    if (base + 3 < N) {
        h = *(const int4*)(hist + base);
    } else {
        if (base + 0 < N) h.x = hist[base + 0];
        if (base + 1 < N) h.y = hist[base + 1];
        if (base + 2 < N) h.z = hist[base + 2];
    }
    int s = h.x + h.y + h.z + h.w;
    ts[t] = s;
    __syncthreads();
    for (int off = 1; off < 256; off <<= 1) {
        int v = ts[t];
        int add = (t >= off) ? ts[t - off] : 0;
        __syncthreads();
        ts[t] = v + add;
        __syncthreads();
    }
    int excl = ts[t] - s;
    int4 o;
    o.x = excl;
    o.y = o.x + h.x;
    o.z = o.y + h.y;
    o.w = o.z + h.z;
    if (base + 3 < N) {
        *(int4*)(offsets + base) = o;
    } else {
        if (base + 0 < N) offsets[base + 0] = o.x;
        if (base + 1 < N) offsets[base + 1] = o.y;
        if (base + 2 < N) offsets[base + 2] = o.z;
    }
    if (t == 255) blockSums[b] = ts[255];
}

__global__ __launch_bounds__(256) void scan_finalize_kernel(
    const int* __restrict__ blockSums, int* __restrict__ offsets,
    int* __restrict__ cursor, int N, int NB)
{
    __shared__ int sPrefix;
    int b = blockIdx.x, t = threadIdx.x;
    if (t < 64) {
        int v = (t < NB) ? blockSums[t] : 0;
        #pragma unroll
        for (int off = 1; off < 64; off <<= 1) {
            int u = __shfl_up(v, off, 64);
            if (t >= off) v += u;
        }
        int pre = __shfl(v, (b == 0) ? 0 : b - 1, 64);
        if (b == 0) pre = 0;
        int total = __shfl(v, NB - 1, 64);
        if (t == 0) {
            sPrefix = pre;
            if (b == 0) offsets[N] = total;
        }
    }
    __syncthreads();
    int prefix = sPrefix;
    int base = b * SCAN_BINS + t * 4;
    if (base + 3 < N) {
        int4 o = *(int4*)(offsets + base);
        o.x += prefix; o.y += prefix; o.z += prefix; o.w += prefix;
        *(int4*)(offsets + base) = o;
        *(int4*)(cursor + base) = o;
    } else {
        for (int j = 0; j < 4; j++) {
            int i = base + j;
            if (i < N) {
                int v = offsets[i] + prefix;
                offsets[i] = v;
                cursor[i] = v;
            }
        }
    }
}

__global__ __launch_bounds__(1024) void scan_kernel(
    const int* __restrict__ hist, int* __restrict__ offsets,
    int* __restrict__ cursor, int N)
{
    __shared__ int ssum[1024];
    int t = threadIdx.x;
    int chunk = (N + 1023) / 1024;
    int lo = t * chunk;
    int hi = lo + chunk; if (hi > N) hi = N;
    int s = 0;
    for (int i = lo; i < hi; i++) s += hist[i];
    ssum[t] = s;
    __syncthreads();
    for (int off = 1; off < 1024; off <<= 1) {
        int v = ssum[t];
        int add = (t >= off) ? ssum[t - off] : 0;
        __syncthreads();
        ssum[t] = v + add;
        __syncthreads();
    }
    int excl = ssum[t] - s;
    for (int i = lo; i < hi; i++) {
        offsets[i] = excl;
        cursor[i] = excl;
        excl += hist[i];
    }
    if (t == 1023) offsets[N] = ssum[1023];
}

__global__ __launch_bounds__(256) void reorder_kernel(
    const int* __restrict__ eidx, int* __restrict__ cursor,
    int* __restrict__ srcSorted, int E)
{
    int i = blockIdx.x * blockDim.x + threadIdx.x;
    int stride = gridDim.x * blockDim.x;
    for (int e = i; e < E; e += stride) {
        int s = eidx[e];
        int t = eidx[E + e];
        int pos = atomicAdd(&cursor[t], 1);
        srcSorted[pos] = s;
    }
}

// 32 lanes per row, 8 rows per block; gathers bf16 x rows, accumulates fp32,
// adds coef * x_self (fp32 source), stores agg as bf16.
__global__ __launch_bounds__(256) void aggregate_kernel(
    const float* __restrict__ x, const unsigned short* __restrict__ xB,
    const int* __restrict__ offsets, const int* __restrict__ srcSorted,
    const float* __restrict__ eps, unsigned short* __restrict__ aggB, int N)
{
    int t = threadIdx.x;
    int tx = t & 31, ty = t >> 5;
    int row = blockIdx.x * 8 + ty;
    if (row >= N) return;
    float coef = 1.0f + eps[0];
    int col = tx * 4;
    float4 xv = *(const float4*)(x + (size_t)row * HDIM + col);
    float4 acc;
    acc.x = coef * xv.x; acc.y = coef * xv.y;
    acc.z = coef * xv.z; acc.w = coef * xv.w;
    int beg = offsets[row], end = offsets[row + 1];
    for (int e = beg; e < end; e++) {
        int s = srcSorted[e];
        ushort4 u = *(const ushort4*)(xB + (size_t)s * HDIM + col);
        // bf16 -> fp32: shift into high half
        union { unsigned u; float f; } c0, c1, c2, c3;
        c0.u = (unsigned)u.x << 16; c1.u = (unsigned)u.y << 16;
        c2.u = (unsigned)u.z << 16; c3.u = (unsigned)u.w << 16;
        acc.x += c0.f; acc.y += c1.f; acc.z += c2.f; acc.w += c3.f;
    }
    ushort4 o;
    o.x = f2b(acc.x); o.y = f2b(acc.y); o.z = f2b(acc.z); o.w = f2b(acc.w);
    *(ushort4*)(aggB + (size_t)row * HDIM + col) = o;
}

// ---------------------------------------------------------------------------
// MFMA GEMM1: h1 = relu(agg @ W1^T + b1), bf16 in, bf16 out. No LDS.
// Wave: 16 rows x 128 cols (8 tiles of 16x16x32). Block: 4 waves = 64 rows.
// A frag: lane(m=l&15,q=l>>4) reads agg[row=rb+m][k=q*8..+7] (16B contig).
// B frag: lane reads W[col=tc*16+m][k=q*8..+7] (16B contig, W L1-resident).
// C/D: col=l&15, row=(l>>4)*4+reg.
// ---------------------------------------------------------------------------
__global__ __launch_bounds__(256) void gemm1_mfma(
    const unsigned short* __restrict__ aggB, const unsigned short* __restrict__ WB,
    const float* __restrict__ bias, unsigned short* __restrict__ h1B, int N)
{
    int w = threadIdx.x >> 6;
    int l = threadIdx.x & 63;
    int m = l & 15, quad = l >> 4;
    int rb = blockIdx.x * 64 + w * 16;
    int rowA = rb + m; if (rowA >= N) rowA = N - 1;

    floatx4 acc[8];
    #pragma unroll
    for (int t = 0; t < 8; t++) acc[t] = (floatx4){0.f, 0.f, 0.f, 0.f};

    #pragma unroll
    for (int kk = 0; kk < 4; kk++) {
        int k0 = kk * 32 + quad * 8;
        short8 a = *(const short8*)(aggB + (size_t)rowA * HDIM + k0);
        #pragma unroll
        for (int t = 0; t < 8; t++) {
            short8 b = *(const short8*)(WB + (size_t)(t * 16 + m) * HDIM + k0);
            acc[t] = __builtin_amdgcn_mfma_f32_16x16x32_bf16(a, b, acc[t], 0, 0, 0);
        }
    }

    int row0 = rb + quad * 4;
    #pragma unroll
    for (int t = 0; t < 8; t++) {
        int col = t * 16 + m;
        float bs = bias[col];
        #pragma unroll
        for (int r = 0; r < 4; r++) {
            int row = row0 + r;
            if (row < N) {
                float v = fmaxf(acc[t][r] + bs, 0.f);
                h1B[(size_t)row * HDIM + col] = f2b(v);
            }
        }
    }
}

// ---------------------------------------------------------------------------
// MFMA GEMM2: out = h1 @ W2^T + b2 (fp32 out) + fused BN column stats
// ---------------------------------------------------------------------------
__global__ __launch_bounds__(256) void gemm2_mfma(
    const unsigned short* __restrict__ h1B, const unsigned short* __restrict__ WB,
    const float* __restrict__ bias, float* __restrict__ out,
    float* __restrict__ statSum, float* __restrict__ statSqs, int N)
{
    __shared__ float sSum[HDIM];
    __shared__ float sSqs[HDIM];
    int w = threadIdx.x >> 6;
    int l = threadIdx.x & 63;
    int m = l & 15, quad = l >> 4;
    int rb = blockIdx.x * 64 + w * 16;
    int rowA = rb + m; if (rowA >= N) rowA = N - 1;
    if (threadIdx.x < HDIM) { sSum[threadIdx.x] = 0.f; sSqs[threadIdx.x] = 0.f; }
    __syncthreads();

    floatx4 acc[8];
    #pragma unroll
    for (int t = 0; t < 8; t++) acc[t] = (floatx4){0.f, 0.f, 0.f, 0.f};

    #pragma unroll
    for (int kk = 0; kk < 4; kk++) {
        int k0 = kk * 32 + quad * 8;
        short8 a = *(const short8*)(h1B + (size_t)rowA * HDIM + k0);
        #pragma unroll
        for (int t = 0; t < 8; t++) {
            short8 b = *(const short8*)(WB + (size_t)(t * 16 + m) * HDIM + k0);
            acc[t] = __builtin_amdgcn_mfma_f32_16x16x32_bf16(a, b, acc[t], 0, 0, 0);
        }
    }

    int row0 = rb + quad * 4;
    #pragma unroll
    for (int t = 0; t < 8; t++) {
        int col = t * 16 + m;
        float bs = bias[col];
        float cs = 0.f, cq = 0.f;
        #pragma unroll
        for (int r = 0; r < 4; r++) {
            int row = row0 + r;
            if (row < N) {
                float v = acc[t][r] + bs;
                out[(size_t)row * HDIM + col] = v;
                cs += v; cq += v * v;
            }
        }
        // reduce over the quad dimension (lanes m, m+16, m+32, m+48)
        cs += __shfl_xor(cs, 16, 64);
        cs += __shfl_xor(cs, 32, 64);
        cq += __shfl_xor(cq, 16, 64);
        cq += __shfl_xor(cq, 32, 64);
        if (quad == 0) {
            atomicAdd(&sSum[col], cs);
            atomicAdd(&sSqs[col], cq);
        }
    }
    __syncthreads();
    if (threadIdx.x < HDIM) {
        atomicAdd(&statSum[threadIdx.x], sSum[threadIdx.x]);
        atomicAdd(&statSqs[threadIdx.x], sSqs[threadIdx.x]);
    }
}

__global__ void bn_prep_kernel(
    const float* __restrict__ statSum, const float* __restrict__ statSqs,
    const float* __restrict__ gamma, const float* __restrict__ beta,
    float* __restrict__ scale, float* __restrict__ shift, int N)
{
    int c = threadIdx.x;
    float invN = 1.0f / (float)N;
    float mean = statSum[c] * invN;
    float var = statSqs[c] * invN - mean * mean;
    float sc = gamma[c] * rsqrtf(var + BN_EPS);
    scale[c] = sc;
    shift[c] = beta[c] - mean * sc;
}

__global__ __launch_bounds__(256) void bn_apply_kernel(
    float* __restrict__ out, const float* __restrict__ scale,
    const float* __restrict__ shift, long n4)
{
    long i = (long)blockIdx.x * blockDim.x + threadIdx.x;
    if (i >= n4) return;
    int cg = (int)(i & 31) * 4;
    float4 v = ((float4*)out)[i];
    float4 sc = *(const float4*)(scale + cg);
    float4 sh = *(const float4*)(shift + cg);
    v.x = fmaxf(v.x * sc.x + sh.x, 0.f);
    v.y = fmaxf(v.y * sc.y + sh.y, 0.f);
    v.z = fmaxf(v.z * sc.z + sh.z, 0.f);
    v.w = fmaxf(v.w * sc.w + sh.w, 0.f);
    ((float4*)out)[i] = v;
}

extern "C" void kernel_launch(void* const* d_in, const int* in_sizes, int n_in,
                              void* d_out, int out_size, void* d_ws, size_t ws_size,
                              hipStream_t stream) {
    const float* x     = (const float*)d_in[0];
    const int*   eidx  = (const int*)d_in[1];
    const float* eps   = (const float*)d_in[2];
    const float* W1    = (const float*)d_in[3];
    const float* b1    = (const float*)d_in[4];
    const float* W2    = (const float*)d_in[5];
    const float* b2    = (const float*)d_in[6];
    const float* gamma = (const float*)d_in[7];
    const float* beta  = (const float*)d_in[8];
    float* out = (float*)d_out;

    int N = in_sizes[0] / HDIM;
    int E = in_sizes[1] / 2;
    size_t NH = (size_t)N * HDIM;
    int NB = (N + SCAN_BINS - 1) / SCAN_BINS;
    int NpadOff = (N + 1 + 3) & ~3;

    // bf16 buffers first (even element counts keep alignment)
    unsigned short* aggB = (unsigned short*)d_ws;   // NH
    unsigned short* h1B  = aggB + NH;               // NH
    unsigned short* xB   = h1B + NH;                // NH
    unsigned short* W1B  = xB + NH;                 // H*H
    unsigned short* W2B  = W1B + HDIM * HDIM;       // H*H
    float* statSum = (float*)(W2B + HDIM * HDIM);   // H
    float* statSqs = statSum + HDIM;
    float* bnScale = statSqs + HDIM;
    float* bnShift = bnScale + HDIM;
    int*   hist    = (int*)(bnShift + HDIM);        // N
    int*   offsets = hist + N;                      // NpadOff
    int*   cursor  = offsets + NpadOff;             // N
    int*   srcSorted = cursor + N;                  // E
    int*   blockSums = srcSorted + E;               // NB

    hipMemsetAsync(statSum, 0, 2 * HDIM * sizeof(float), stream);
    hipMemsetAsync(hist, 0, (size_t)N * sizeof(int), stream);

    // dtype conversions (independent of sort chain)
    convert_w_kernel<<<(HDIM * HDIM) / 256, 256, 0, stream>>>(W1, W2, W1B, W2B);
    long n4 = (long)NH / 4;
    convert_x_kernel<<<(int)((n4 + 255) / 256), 256, 0, stream>>>(x, xB, n4);

    // counting sort of edges by target
    hist_kernel<<<512, 256, 0, stream>>>(eidx, hist, E);
    if (NB <= 64) {
        block_scan_kernel<<<NB, 256, 0, stream>>>(hist, offsets, blockSums, N);
        scan_finalize_kernel<<<NB, 256, 0, stream>>>(blockSums, offsets, cursor, N, NB);
    } else {
        scan_kernel<<<1, 1024, 0, stream>>>(hist, offsets, cursor, N);
    }
    reorder_kernel<<<512, 256, 0, stream>>>(eidx, cursor, srcSorted, E);
    aggregate_kernel<<<(N + 7) / 8, 256, 0, stream>>>(x, xB, offsets, srcSorted, eps, aggB, N);

    // MFMA GEMMs
    int gblocks = (N + 63) / 64;
    gemm1_mfma<<<gblocks, 256, 0, stream>>>(aggB, W1B, b1, h1B, N);
    gemm2_mfma<<<gblocks, 256, 0, stream>>>(h1B, W2B, b2, out, statSum, statSqs, N);

    bn_prep_kernel<<<1, HDIM, 0, stream>>>(statSum, statSqs, gamma, beta, bnScale, bnShift, N);
    bn_apply_kernel<<<(int)((n4 + 255) / 256), 256, 0, stream>>>(out, bnScale, bnShift, n4);
}

// Round 5
// 250.735 us; speedup vs baseline: 5.1812x; 1.0803x over previous
//
#include <hip/hip_runtime.h>

#define HDIM 128
#define BN_EPS 1e-5f
#define SCAN_BINS 1024
#define NPART 8   // XCD count: target-range partitions for reorder

typedef short short8 __attribute__((ext_vector_type(8)));
typedef float floatx4 __attribute__((ext_vector_type(4)));

__device__ __forceinline__ unsigned short f2b(float f) {
    union { float f; unsigned u; } v; v.f = f;
    unsigned r = v.u + 0x7FFFu + ((v.u >> 16) & 1u);   // RNE
    return (unsigned short)(r >> 16);
}

// ---------------------------------------------------------------------------
// Converters: weights and x to bf16
// ---------------------------------------------------------------------------
__global__ __launch_bounds__(256) void convert_w_kernel(
    const float* __restrict__ W1, const float* __restrict__ W2,
    unsigned short* __restrict__ W1B, unsigned short* __restrict__ W2B)
{
    int i = blockIdx.x * 256 + threadIdx.x;   // 16384 total
    W1B[i] = f2b(W1[i]);
    W2B[i] = f2b(W2[i]);
}

__global__ __launch_bounds__(256) void convert_x_kernel(
    const float* __restrict__ x, unsigned short* __restrict__ xB, long n4)
{
    long i = (long)blockIdx.x * 256 + threadIdx.x;
    if (i >= n4) return;
    float4 v = ((const float4*)x)[i];
    ushort4 o;
    o.x = f2b(v.x); o.y = f2b(v.y); o.z = f2b(v.z); o.w = f2b(v.w);
    ((ushort4*)xB)[i] = o;
}

// ---------------------------------------------------------------------------
// Counting-sort path
// ---------------------------------------------------------------------------
__global__ __launch_bounds__(256) void hist_kernel(
    const int* __restrict__ eidx, int* __restrict__ hist, int E)
{
    int i = blockIdx.x * blockDim.x + threadIdx.x;
    int stride = gridDim.x * blockDim.x;
    for (int e = i; e < E; e += stride) {
        atomicAdd(&hist[eidx[E + e]], 1);
    }
}

__global__ __launch_bounds__(256) void block_scan_kernel(
    const int* __restrict__ hist, int* __restrict__ offsets,
    int* __restrict__ blockSums, int N)
{
    __shared__ int ts[256];
    int b = blockIdx.x, t = threadIdx.x;
    int base = b * SCAN_BINS + t * 4;
    int4 h = make_int4(0, 0, 0, 0);
    if (base + 3 < N) {
        h = *(const int4*)(hist + base);
    } else {
        if (base + 0 < N) h.x = hist[base + 0];
        if (base + 1 < N) h.y = hist[base + 1];
        if (base + 2 < N) h.z = hist[base + 2];
    }
    int s = h.x + h.y + h.z + h.w;
    ts[t] = s;
    __syncthreads();
    for (int off = 1; off < 256; off <<= 1) {
        int v = ts[t];
        int add = (t >= off) ? ts[t - off] : 0;
        __syncthreads();
        ts[t] = v + add;
        __syncthreads();
    }
    int excl = ts[t] - s;
    int4 o;
    o.x = excl;
    o.y = o.x + h.x;
    o.z = o.y + h.y;
    o.w = o.z + h.z;
    if (base + 3 < N) {
        *(int4*)(offsets + base) = o;
    } else {
        if (base + 0 < N) offsets[base + 0] = o.x;
        if (base + 1 < N) offsets[base + 1] = o.y;
        if (base + 2 < N) offsets[base + 2] = o.z;
    }
    if (t == 255) blockSums[b] = ts[255];
}

__global__ __launch_bounds__(256) void scan_finalize_kernel(
    const int* __restrict__ blockSums, int* __restrict__ offsets,
    int* __restrict__ cursor, int N, int NB)
{
    __shared__ int sPrefix;
    int b = blockIdx.x, t = threadIdx.x;
    if (t < 64) {
        int v = (t < NB) ? blockSums[t] : 0;
        #pragma unroll
        for (int off = 1; off < 64; off <<= 1) {
            int u = __shfl_up(v, off, 64);
            if (t >= off) v += u;
        }
        int pre = __shfl(v, (b == 0) ? 0 : b - 1, 64);
        if (b == 0) pre = 0;
        int total = __shfl(v, NB - 1, 64);
        if (t == 0) {
            sPrefix = pre;
            if (b == 0) offsets[N] = total;
        }
    }
    __syncthreads();
    int prefix = sPrefix;
    int base = b * SCAN_BINS + t * 4;
    if (base + 3 < N) {
        int4 o = *(int4*)(offsets + base);
        o.x += prefix; o.y += prefix; o.z += prefix; o.w += prefix;
        *(int4*)(offsets + base) = o;
        *(int4*)(cursor + base) = o;
    } else {
        for (int j = 0; j < 4; j++) {
            int i = base + j;
            if (i < N) {
                int v = offsets[i] + prefix;
                offsets[i] = v;
                cursor[i] = v;
            }
        }
    }
}

__global__ __launch_bounds__(1024) void scan_kernel(
    const int* __restrict__ hist, int* __restrict__ offsets,
    int* __restrict__ cursor, int N)
{
    __shared__ int ssum[1024];
    int t = threadIdx.x;
    int chunk = (N + 1023) / 1024;
    int lo = t * chunk;
    int hi = lo + chunk; if (hi > N) hi = N;
    int s = 0;
    for (int i = lo; i < hi; i++) s += hist[i];
    ssum[t] = s;
    __syncthreads();
    for (int off = 1; off < 1024; off <<= 1) {
        int v = ssum[t];
        int add = (t >= off) ? ssum[t - off] : 0;
        __syncthreads();
        ssum[t] = v + add;
        __syncthreads();
    }
    int excl = ssum[t] - s;
    for (int i = lo; i < hi; i++) {
        offsets[i] = excl;
        cursor[i] = excl;
        excl += hist[i];
    }
    if (t == 1023) offsets[N] = ssum[1023];
}

// XCD-partitioned reorder: partition p = blockIdx&7 handles target range
// [p*partSize, (p+1)*partSize). All of p's cursor segment + srcSorted window
// stay in one XCD's L2 (blockIdx%8 ~ XCD round-robin heuristic; correctness
// does not depend on the mapping). tgt re-reads are LLC-served.
__global__ __launch_bounds__(256) void reorder_kernel(
    const int* __restrict__ eidx, int* __restrict__ cursor,
    int* __restrict__ srcSorted, int E, int partSize)
{
    int part = blockIdx.x & (NPART - 1);
    int bi = blockIdx.x >> 3;           // block index within partition
    int nb = gridDim.x >> 3;            // blocks per partition
    int lo = part * partSize;
    int hi = lo + partSize;
    int stride = nb * 256;
    for (int e = bi * 256 + threadIdx.x; e < E; e += stride) {
        int t = eidx[E + e];
        if (t >= lo && t < hi) {
            int pos = atomicAdd(&cursor[t], 1);
            srcSorted[pos] = eidx[e];
        }
    }
}

// 32 lanes per row, 8 rows per block; gathers bf16 x rows (2-way unrolled),
// accumulates fp32, adds coef * x_self (fp32 source), stores agg as bf16.
__global__ __launch_bounds__(256) void aggregate_kernel(
    const float* __restrict__ x, const unsigned short* __restrict__ xB,
    const int* __restrict__ offsets, const int* __restrict__ srcSorted,
    const float* __restrict__ eps, unsigned short* __restrict__ aggB, int N)
{
    int t = threadIdx.x;
    int tx = t & 31, ty = t >> 5;
    int row = blockIdx.x * 8 + ty;
    if (row >= N) return;
    float coef = 1.0f + eps[0];
    int col = tx * 4;
    float4 xv = *(const float4*)(x + (size_t)row * HDIM + col);
    float4 acc;
    acc.x = coef * xv.x; acc.y = coef * xv.y;
    acc.z = coef * xv.z; acc.w = coef * xv.w;
    int beg = offsets[row], end = offsets[row + 1];
    int e = beg;
    for (; e + 1 < end; e += 2) {
        int s0 = srcSorted[e];
        int s1 = srcSorted[e + 1];
        ushort4 u0 = *(const ushort4*)(xB + (size_t)s0 * HDIM + col);
        ushort4 u1 = *(const ushort4*)(xB + (size_t)s1 * HDIM + col);
        union { unsigned u; float f; } c0, c1, c2, c3, d0, d1, d2, d3;
        c0.u = (unsigned)u0.x << 16; c1.u = (unsigned)u0.y << 16;
        c2.u = (unsigned)u0.z << 16; c3.u = (unsigned)u0.w << 16;
        d0.u = (unsigned)u1.x << 16; d1.u = (unsigned)u1.y << 16;
        d2.u = (unsigned)u1.z << 16; d3.u = (unsigned)u1.w << 16;
        acc.x += c0.f + d0.f; acc.y += c1.f + d1.f;
        acc.z += c2.f + d2.f; acc.w += c3.f + d3.f;
    }
    if (e < end) {
        int s = srcSorted[e];
        ushort4 u = *(const ushort4*)(xB + (size_t)s * HDIM + col);
        union { unsigned u; float f; } c0, c1, c2, c3;
        c0.u = (unsigned)u.x << 16; c1.u = (unsigned)u.y << 16;
        c2.u = (unsigned)u.z << 16; c3.u = (unsigned)u.w << 16;
        acc.x += c0.f; acc.y += c1.f; acc.z += c2.f; acc.w += c3.f;
    }
    ushort4 o;
    o.x = f2b(acc.x); o.y = f2b(acc.y); o.z = f2b(acc.z); o.w = f2b(acc.w);
    *(ushort4*)(aggB + (size_t)row * HDIM + col) = o;
}

// ---------------------------------------------------------------------------
// MFMA GEMM1: h1 = relu(agg @ W1^T + b1), bf16 in, bf16 out. No LDS.
// ---------------------------------------------------------------------------
__global__ __launch_bounds__(256) void gemm1_mfma(
    const unsigned short* __restrict__ aggB, const unsigned short* __restrict__ WB,
    const float* __restrict__ bias, unsigned short* __restrict__ h1B, int N)
{
    int w = threadIdx.x >> 6;
    int l = threadIdx.x & 63;
    int m = l & 15, quad = l >> 4;
    int rb = blockIdx.x * 64 + w * 16;
    int rowA = rb + m; if (rowA >= N) rowA = N - 1;

    floatx4 acc[8];
    #pragma unroll
    for (int t = 0; t < 8; t++) acc[t] = (floatx4){0.f, 0.f, 0.f, 0.f};

    #pragma unroll
    for (int kk = 0; kk < 4; kk++) {
        int k0 = kk * 32 + quad * 8;
        short8 a = *(const short8*)(aggB + (size_t)rowA * HDIM + k0);
        #pragma unroll
        for (int t = 0; t < 8; t++) {
            short8 b = *(const short8*)(WB + (size_t)(t * 16 + m) * HDIM + k0);
            acc[t] = __builtin_amdgcn_mfma_f32_16x16x32_bf16(a, b, acc[t], 0, 0, 0);
        }
    }

    int row0 = rb + quad * 4;
    #pragma unroll
    for (int t = 0; t < 8; t++) {
        int col = t * 16 + m;
        float bs = bias[col];
        #pragma unroll
        for (int r = 0; r < 4; r++) {
            int row = row0 + r;
            if (row < N) {
                float v = fmaxf(acc[t][r] + bs, 0.f);
                h1B[(size_t)row * HDIM + col] = f2b(v);
            }
        }
    }
}

// ---------------------------------------------------------------------------
// MFMA GEMM2: out = h1 @ W2^T + b2 (fp32 out) + fused BN column stats
// ---------------------------------------------------------------------------
__global__ __launch_bounds__(256) void gemm2_mfma(
    const unsigned short* __restrict__ h1B, const unsigned short* __restrict__ WB,
    const float* __restrict__ bias, float* __restrict__ out,
    float* __restrict__ statSum, float* __restrict__ statSqs, int N)
{
    __shared__ float sSum[HDIM];
    __shared__ float sSqs[HDIM];
    int w = threadIdx.x >> 6;
    int l = threadIdx.x & 63;
    int m = l & 15, quad = l >> 4;
    int rb = blockIdx.x * 64 + w * 16;
    int rowA = rb + m; if (rowA >= N) rowA = N - 1;
    if (threadIdx.x < HDIM) { sSum[threadIdx.x] = 0.f; sSqs[threadIdx.x] = 0.f; }
    __syncthreads();

    floatx4 acc[8];
    #pragma unroll
    for (int t = 0; t < 8; t++) acc[t] = (floatx4){0.f, 0.f, 0.f, 0.f};

    #pragma unroll
    for (int kk = 0; kk < 4; kk++) {
        int k0 = kk * 32 + quad * 8;
        short8 a = *(const short8*)(h1B + (size_t)rowA * HDIM + k0);
        #pragma unroll
        for (int t = 0; t < 8; t++) {
            short8 b = *(const short8*)(WB + (size_t)(t * 16 + m) * HDIM + k0);
            acc[t] = __builtin_amdgcn_mfma_f32_16x16x32_bf16(a, b, acc[t], 0, 0, 0);
        }
    }

    int row0 = rb + quad * 4;
    #pragma unroll
    for (int t = 0; t < 8; t++) {
        int col = t * 16 + m;
        float bs = bias[col];
        float cs = 0.f, cq = 0.f;
        #pragma unroll
        for (int r = 0; r < 4; r++) {
            int row = row0 + r;
            if (row < N) {
                float v = acc[t][r] + bs;
                out[(size_t)row * HDIM + col] = v;
                cs += v; cq += v * v;
            }
        }
        cs += __shfl_xor(cs, 16, 64);
        cs += __shfl_xor(cs, 32, 64);
        cq += __shfl_xor(cq, 16, 64);
        cq += __shfl_xor(cq, 32, 64);
        if (quad == 0) {
            atomicAdd(&sSum[col], cs);
            atomicAdd(&sSqs[col], cq);
        }
    }
    __syncthreads();
    if (threadIdx.x < HDIM) {
        atomicAdd(&statSum[threadIdx.x], sSum[threadIdx.x]);
        atomicAdd(&statSqs[threadIdx.x], sSqs[threadIdx.x]);
    }
}

__global__ void bn_prep_kernel(
    const float* __restrict__ statSum, const float* __restrict__ statSqs,
    const float* __restrict__ gamma, const float* __restrict__ beta,
    float* __restrict__ scale, float* __restrict__ shift, int N)
{
    int c = threadIdx.x;
    float invN = 1.0f / (float)N;
    float mean = statSum[c] * invN;
    float var = statSqs[c] * invN - mean * mean;
    float sc = gamma[c] * rsqrtf(var + BN_EPS);
    scale[c] = sc;
    shift[c] = beta[c] - mean * sc;
}

__global__ __launch_bounds__(256) void bn_apply_kernel(
    float* __restrict__ out, const float* __restrict__ scale,
    const float* __restrict__ shift, long n4)
{
    long i = (long)blockIdx.x * blockDim.x + threadIdx.x;
    if (i >= n4) return;
    int cg = (int)(i & 31) * 4;
    float4 v = ((float4*)out)[i];
    float4 sc = *(const float4*)(scale + cg);
    float4 sh = *(const float4*)(shift + cg);
    v.x = fmaxf(v.x * sc.x + sh.x, 0.f);
    v.y = fmaxf(v.y * sc.y + sh.y, 0.f);
    v.z = fmaxf(v.z * sc.z + sh.z, 0.f);
    v.w = fmaxf(v.w * sc.w + sh.w, 0.f);
    ((float4*)out)[i] = v;
}

extern "C" void kernel_launch(void* const* d_in, const int* in_sizes, int n_in,
                              void* d_out, int out_size, void* d_ws, size_t ws_size,
                              hipStream_t stream) {
    const float* x     = (const float*)d_in[0];
    const int*   eidx  = (const int*)d_in[1];
    const float* eps   = (const float*)d_in[2];
    const float* W1    = (const float*)d_in[3];
    const float* b1    = (const float*)d_in[4];
    const float* W2    = (const float*)d_in[5];
    const float* b2    = (const float*)d_in[6];
    const float* gamma = (const float*)d_in[7];
    const float* beta  = (const float*)d_in[8];
    float* out = (float*)d_out;

    int N = in_sizes[0] / HDIM;
    int E = in_sizes[1] / 2;
    size_t NH = (size_t)N * HDIM;
    int NB = (N + SCAN_BINS - 1) / SCAN_BINS;
    int NpadOff = (N + 1 + 3) & ~3;
    int partSize = (N + NPART - 1) / NPART;

    unsigned short* aggB = (unsigned short*)d_ws;   // NH
    unsigned short* h1B  = aggB + NH;               // NH
    unsigned short* xB   = h1B + NH;                // NH
    unsigned short* W1B  = xB + NH;                 // H*H
    unsigned short* W2B  = W1B + HDIM * HDIM;       // H*H
    float* statSum = (float*)(W2B + HDIM * HDIM);   // H
    float* statSqs = statSum + HDIM;
    float* bnScale = statSqs + HDIM;
    float* bnShift = bnScale + HDIM;
    int*   hist    = (int*)(bnShift + HDIM);        // N
    int*   offsets = hist + N;                      // NpadOff
    int*   cursor  = offsets + NpadOff;             // N
    int*   srcSorted = cursor + N;                  // E
    int*   blockSums = srcSorted + E;               // NB

    hipMemsetAsync(statSum, 0, 2 * HDIM * sizeof(float), stream);
    hipMemsetAsync(hist, 0, (size_t)N * sizeof(int), stream);

    convert_w_kernel<<<(HDIM * HDIM) / 256, 256, 0, stream>>>(W1, W2, W1B, W2B);
    long n4 = (long)NH / 4;
    convert_x_kernel<<<(int)((n4 + 255) / 256), 256, 0, stream>>>(x, xB, n4);

    hist_kernel<<<512, 256, 0, stream>>>(eidx, hist, E);
    if (NB <= 64) {
        block_scan_kernel<<<NB, 256, 0, stream>>>(hist, offsets, blockSums, N);
        scan_finalize_kernel<<<NB, 256, 0, stream>>>(blockSums, offsets, cursor, N, NB);
    } else {
        scan_kernel<<<1, 1024, 0, stream>>>(hist, offsets, cursor, N);
    }
    reorder_kernel<<<2048, 256, 0, stream>>>(eidx, cursor, srcSorted, E, partSize);
    aggregate_kernel<<<(N + 7) / 8, 256, 0, stream>>>(x, xB, offsets, srcSorted, eps, aggB, N);

    int gblocks = (N + 63) / 64;
    gemm1_mfma<<<gblocks, 256, 0, stream>>>(aggB, W1B, b1, h1B, N);
    gemm2_mfma<<<gblocks, 256, 0, stream>>>(h1B, W2B, b2, out, statSum, statSqs, N);

    bn_prep_kernel<<<1, HDIM, 0, stream>>>(statSum, statSqs, gamma, beta, bnScale, bnShift, N);
    bn_apply_kernel<<<(int)((n4 + 255) / 256), 256, 0, stream>>>(out, bnScale, bnShift, n4);
}

// Round 6
// 225.061 us; speedup vs baseline: 5.7723x; 1.1141x over previous
//
#include <hip/hip_runtime.h>

#define HDIM 128
#define BN_EPS 1e-5f
#define SCAN_BINS 1024
#define NPART 8    // XCD count: target-range partitions for reorder
#define LSTR 136   // LDS row stride (shorts) for h1 tile

typedef short short8 __attribute__((ext_vector_type(8)));
typedef float floatx4 __attribute__((ext_vector_type(4)));

__device__ __forceinline__ unsigned short f2b(float f) {
    union { float f; unsigned u; } v; v.f = f;
    unsigned r = v.u + 0x7FFFu + ((v.u >> 16) & 1u);   // RNE
    return (unsigned short)(r >> 16);
}

__device__ __forceinline__ float b2f(unsigned short b) {
    union { unsigned u; float f; } v; v.u = (unsigned)b << 16;
    return v.f;
}

// ---------------------------------------------------------------------------
// prep: convert x -> bf16, W1/W2 -> bf16, and histogram targets. One kernel.
// ---------------------------------------------------------------------------
__global__ __launch_bounds__(256) void prep_kernel(
    const float* __restrict__ x, unsigned short* __restrict__ xB, long n4,
    const float* __restrict__ W1, const float* __restrict__ W2,
    unsigned short* __restrict__ W1B, unsigned short* __restrict__ W2B,
    const int* __restrict__ eidx, int* __restrict__ hist, int E)
{
    int tid = blockIdx.x * 256 + threadIdx.x;
    int stride = gridDim.x * 256;
    for (long i = tid; i < n4; i += stride) {
        float4 v = ((const float4*)x)[i];
        ushort4 o;
        o.x = f2b(v.x); o.y = f2b(v.y); o.z = f2b(v.z); o.w = f2b(v.w);
        ((ushort4*)xB)[i] = o;
    }
    for (int i = tid; i < HDIM * HDIM; i += stride) {
        W1B[i] = f2b(W1[i]);
        W2B[i] = f2b(W2[i]);
    }
    for (int e = tid; e < E; e += stride) {
        atomicAdd(&hist[eidx[E + e]], 1);
    }
}

// ---------------------------------------------------------------------------
// Two-level scan
// ---------------------------------------------------------------------------
__global__ __launch_bounds__(256) void block_scan_kernel(
    const int* __restrict__ hist, int* __restrict__ offsets,
    int* __restrict__ blockSums, int N)
{
    __shared__ int ts[256];
    int b = blockIdx.x, t = threadIdx.x;
    int base = b * SCAN_BINS + t * 4;
    int4 h = make_int4(0, 0, 0, 0);
    if (base + 3 < N) {
        h = *(const int4*)(hist + base);
    } else {
        if (base + 0 < N) h.x = hist[base + 0];
        if (base + 1 < N) h.y = hist[base + 1];
        if (base + 2 < N) h.z = hist[base + 2];
    }
    int s = h.x + h.y + h.z + h.w;
    ts[t] = s;
    __syncthreads();
    for (int off = 1; off < 256; off <<= 1) {
        int v = ts[t];
        int add = (t >= off) ? ts[t - off] : 0;
        __syncthreads();
        ts[t] = v + add;
        __syncthreads();
    }
    int excl = ts[t] - s;
    int4 o;
    o.x = excl;
    o.y = o.x + h.x;
    o.z = o.y + h.y;
    o.w = o.z + h.z;
    if (base + 3 < N) {
        *(int4*)(offsets + base) = o;
    } else {
        if (base + 0 < N) offsets[base + 0] = o.x;
        if (base + 1 < N) offsets[base + 1] = o.y;
        if (base + 2 < N) offsets[base + 2] = o.z;
    }
    if (t == 255) blockSums[b] = ts[255];
}

__global__ __launch_bounds__(256) void scan_finalize_kernel(
    const int* __restrict__ blockSums, int* __restrict__ offsets,
    int* __restrict__ cursor, int N, int NB)
{
    __shared__ int sPrefix;
    int b = blockIdx.x, t = threadIdx.x;
    if (t < 64) {
        int v = (t < NB) ? blockSums[t] : 0;
        #pragma unroll
        for (int off = 1; off < 64; off <<= 1) {
            int u = __shfl_up(v, off, 64);
            if (t >= off) v += u;
        }
        int pre = __shfl(v, (b == 0) ? 0 : b - 1, 64);
        if (b == 0) pre = 0;
        int total = __shfl(v, NB - 1, 64);
        if (t == 0) {
            sPrefix = pre;
            if (b == 0) offsets[N] = total;
        }
    }
    __syncthreads();
    int prefix = sPrefix;
    int base = b * SCAN_BINS + t * 4;
    if (base + 3 < N) {
        int4 o = *(int4*)(offsets + base);
        o.x += prefix; o.y += prefix; o.z += prefix; o.w += prefix;
        *(int4*)(offsets + base) = o;
        *(int4*)(cursor + base) = o;
    } else {
        for (int j = 0; j < 4; j++) {
            int i = base + j;
            if (i < N) {
                int v = offsets[i] + prefix;
                offsets[i] = v;
                cursor[i] = v;
            }
        }
    }
}

__global__ __launch_bounds__(1024) void scan_kernel(
    const int* __restrict__ hist, int* __restrict__ offsets,
    int* __restrict__ cursor, int N)
{
    __shared__ int ssum[1024];
    int t = threadIdx.x;
    int chunk = (N + 1023) / 1024;
    int lo = t * chunk;
    int hi = lo + chunk; if (hi > N) hi = N;
    int s = 0;
    for (int i = lo; i < hi; i++) s += hist[i];
    ssum[t] = s;
    __syncthreads();
    for (int off = 1; off < 1024; off <<= 1) {
        int v = ssum[t];
        int add = (t >= off) ? ssum[t - off] : 0;
        __syncthreads();
        ssum[t] = v + add;
        __syncthreads();
    }
    int excl = ssum[t] - s;
    for (int i = lo; i < hi; i++) {
        offsets[i] = excl;
        cursor[i] = excl;
        excl += hist[i];
    }
    if (t == 1023) offsets[N] = ssum[1023];
}

// XCD-partitioned reorder (blockIdx%8 ~ XCD round-robin; perf heuristic only)
__global__ __launch_bounds__(256) void reorder_kernel(
    const int* __restrict__ eidx, int* __restrict__ cursor,
    int* __restrict__ srcSorted, int E, int partSize)
{
    int part = blockIdx.x & (NPART - 1);
    int bi = blockIdx.x >> 3;
    int nb = gridDim.x >> 3;
    int lo = part * partSize;
    int hi = lo + partSize;
    int stride = nb * 256;
    for (int e = bi * 256 + threadIdx.x; e < E; e += stride) {
        int t = eidx[E + e];
        if (t >= lo && t < hi) {
            int pos = atomicAdd(&cursor[t], 1);
            srcSorted[pos] = eidx[e];
        }
    }
}

// 16 lanes per row (16B ushort8 loads), 16 rows per block, 2-edge unroll.
__global__ __launch_bounds__(256) void aggregate_kernel(
    const float* __restrict__ x, const unsigned short* __restrict__ xB,
    const int* __restrict__ offsets, const int* __restrict__ srcSorted,
    const float* __restrict__ eps, unsigned short* __restrict__ aggB, int N)
{
    int t = threadIdx.x;
    int tx = t & 15, ty = t >> 4;
    int row = blockIdx.x * 16 + ty;
    if (row >= N) return;
    float coef = 1.0f + eps[0];
    int col = tx * 8;
    float4 xv0 = *(const float4*)(x + (size_t)row * HDIM + col);
    float4 xv1 = *(const float4*)(x + (size_t)row * HDIM + col + 4);
    float acc[8];
    acc[0] = coef * xv0.x; acc[1] = coef * xv0.y;
    acc[2] = coef * xv0.z; acc[3] = coef * xv0.w;
    acc[4] = coef * xv1.x; acc[5] = coef * xv1.y;
    acc[6] = coef * xv1.z; acc[7] = coef * xv1.w;
    int beg = offsets[row], end = offsets[row + 1];
    int e = beg;
    for (; e + 1 < end; e += 2) {
        int s0 = srcSorted[e];
        int s1 = srcSorted[e + 1];
        short8 u0 = *(const short8*)(xB + (size_t)s0 * HDIM + col);
        short8 u1 = *(const short8*)(xB + (size_t)s1 * HDIM + col);
        #pragma unroll
        for (int j = 0; j < 8; j++)
            acc[j] += b2f((unsigned short)u0[j]) + b2f((unsigned short)u1[j]);
    }
    if (e < end) {
        int s = srcSorted[e];
        short8 u = *(const short8*)(xB + (size_t)s * HDIM + col);
        #pragma unroll
        for (int j = 0; j < 8; j++)
            acc[j] += b2f((unsigned short)u[j]);
    }
    short8 o;
    #pragma unroll
    for (int j = 0; j < 8; j++) o[j] = (short)f2b(acc[j]);
    *(short8*)(aggB + (size_t)row * HDIM + col) = o;
}

// ---------------------------------------------------------------------------
// Fused MFMA GEMM1+GEMM2: h1 = relu(agg@W1^T+b1) kept in LDS (C->A layout
// transform), then out = h1@W2^T+b2 (fp32) + fused BN column stats.
// Wave: 16 rows x 128 cols. Block: 4 waves = 64 rows.
// ---------------------------------------------------------------------------
__global__ __launch_bounds__(256) void gemm_fused(
    const unsigned short* __restrict__ aggB,
    const unsigned short* __restrict__ W1B, const float* __restrict__ b1,
    const unsigned short* __restrict__ W2B, const float* __restrict__ b2,
    float* __restrict__ out,
    float* __restrict__ statSum, float* __restrict__ statSqs, int N)
{
    __shared__ unsigned short sH[4 * 16 * LSTR];   // 17408 B
    __shared__ float sSum[HDIM];
    __shared__ float sSqs[HDIM];
    int w = threadIdx.x >> 6;
    int l = threadIdx.x & 63;
    int m = l & 15, quad = l >> 4;
    int rb = blockIdx.x * 64 + w * 16;
    int rowA = rb + m; if (rowA >= N) rowA = N - 1;
    if (threadIdx.x < HDIM) { sSum[threadIdx.x] = 0.f; sSqs[threadIdx.x] = 0.f; }

    // ---- GEMM1 ----
    floatx4 acc[8];
    #pragma unroll
    for (int t = 0; t < 8; t++) acc[t] = (floatx4){0.f, 0.f, 0.f, 0.f};
    #pragma unroll
    for (int kk = 0; kk < 4; kk++) {
        int k0 = kk * 32 + quad * 8;
        short8 a = *(const short8*)(aggB + (size_t)rowA * HDIM + k0);
        #pragma unroll
        for (int t = 0; t < 8; t++) {
            short8 b = *(const short8*)(W1B + (size_t)(t * 16 + m) * HDIM + k0);
            acc[t] = __builtin_amdgcn_mfma_f32_16x16x32_bf16(a, b, acc[t], 0, 0, 0);
        }
    }
    // epilogue1: relu+bias, C-layout -> row-major LDS (A-layout source)
    unsigned short* myH = sH + w * 16 * LSTR;
    #pragma unroll
    for (int t = 0; t < 8; t++) {
        int col = t * 16 + m;
        float bs = b1[col];
        #pragma unroll
        for (int r = 0; r < 4; r++) {
            float v = fmaxf(acc[t][r] + bs, 0.f);
            myH[(quad * 4 + r) * LSTR + col] = f2b(v);
        }
    }
    __syncthreads();

    // ---- GEMM2 from LDS ----
    floatx4 acc2[8];
    #pragma unroll
    for (int t = 0; t < 8; t++) acc2[t] = (floatx4){0.f, 0.f, 0.f, 0.f};
    #pragma unroll
    for (int kk = 0; kk < 4; kk++) {
        int k0 = kk * 32 + quad * 8;
        short8 a = *(const short8*)(myH + m * LSTR + k0);
        #pragma unroll
        for (int t = 0; t < 8; t++) {
            short8 b = *(const short8*)(W2B + (size_t)(t * 16 + m) * HDIM + k0);
            acc2[t] = __builtin_amdgcn_mfma_f32_16x16x32_bf16(a, b, acc2[t], 0, 0, 0);
        }
    }
    // epilogue2: bias, store fp32 out, BN stats
    int row0 = rb + quad * 4;
    #pragma unroll
    for (int t = 0; t < 8; t++) {
        int col = t * 16 + m;
        float bs = b2[col];
        float cs = 0.f, cq = 0.f;
        #pragma unroll
        for (int r = 0; r < 4; r++) {
            int row = row0 + r;
            if (row < N) {
                float v = acc2[t][r] + bs;
                out[(size_t)row * HDIM + col] = v;
                cs += v; cq += v * v;
            }
        }
        cs += __shfl_xor(cs, 16, 64);
        cs += __shfl_xor(cs, 32, 64);
        cq += __shfl_xor(cq, 16, 64);
        cq += __shfl_xor(cq, 32, 64);
        if (quad == 0) {
            atomicAdd(&sSum[col], cs);
            atomicAdd(&sSqs[col], cq);
        }
    }
    __syncthreads();
    if (threadIdx.x < HDIM) {
        atomicAdd(&statSum[threadIdx.x], sSum[threadIdx.x]);
        atomicAdd(&statSqs[threadIdx.x], sSqs[threadIdx.x]);
    }
}

__global__ void bn_prep_kernel(
    const float* __restrict__ statSum, const float* __restrict__ statSqs,
    const float* __restrict__ gamma, const float* __restrict__ beta,
    float* __restrict__ scale, float* __restrict__ shift, int N)
{
    int c = threadIdx.x;
    float invN = 1.0f / (float)N;
    float mean = statSum[c] * invN;
    float var = statSqs[c] * invN - mean * mean;
    float sc = gamma[c] * rsqrtf(var + BN_EPS);
    scale[c] = sc;
    shift[c] = beta[c] - mean * sc;
}

__global__ __launch_bounds__(256) void bn_apply_kernel(
    float* __restrict__ out, const float* __restrict__ scale,
    const float* __restrict__ shift, long n4)
{
    long i = (long)blockIdx.x * blockDim.x + threadIdx.x;
    if (i >= n4) return;
    int cg = (int)(i & 31) * 4;
    float4 v = ((float4*)out)[i];
    float4 sc = *(const float4*)(scale + cg);
    float4 sh = *(const float4*)(shift + cg);
    v.x = fmaxf(v.x * sc.x + sh.x, 0.f);
    v.y = fmaxf(v.y * sc.y + sh.y, 0.f);
    v.z = fmaxf(v.z * sc.z + sh.z, 0.f);
    v.w = fmaxf(v.w * sc.w + sh.w, 0.f);
    ((float4*)out)[i] = v;
}

extern "C" void kernel_launch(void* const* d_in, const int* in_sizes, int n_in,
                              void* d_out, int out_size, void* d_ws, size_t ws_size,
                              hipStream_t stream) {
    const float* x     = (const float*)d_in[0];
    const int*   eidx  = (const int*)d_in[1];
    const float* eps   = (const float*)d_in[2];
    const float* W1    = (const float*)d_in[3];
    const float* b1    = (const float*)d_in[4];
    const float* W2    = (const float*)d_in[5];
    const float* b2    = (const float*)d_in[6];
    const float* gamma = (const float*)d_in[7];
    const float* beta  = (const float*)d_in[8];
    float* out = (float*)d_out;

    int N = in_sizes[0] / HDIM;
    int E = in_sizes[1] / 2;
    size_t NH = (size_t)N * HDIM;
    int NB = (N + SCAN_BINS - 1) / SCAN_BINS;
    int NpadOff = (N + 1 + 3) & ~3;
    int partSize = (N + NPART - 1) / NPART;

    unsigned short* aggB = (unsigned short*)d_ws;   // NH
    unsigned short* xB   = aggB + NH;               // NH
    unsigned short* W1B  = xB + NH;                 // H*H
    unsigned short* W2B  = W1B + HDIM * HDIM;       // H*H
    float* statSum = (float*)(W2B + HDIM * HDIM);   // H
    float* statSqs = statSum + HDIM;
    float* bnScale = statSqs + HDIM;
    float* bnShift = bnScale + HDIM;
    int*   hist    = (int*)(bnShift + HDIM);        // N
    int*   offsets = hist + N;                      // NpadOff
    int*   cursor  = offsets + NpadOff;             // N
    int*   srcSorted = cursor + N;                  // E
    int*   blockSums = srcSorted + E;               // NB

    hipMemsetAsync(statSum, 0, 2 * HDIM * sizeof(float), stream);
    hipMemsetAsync(hist, 0, (size_t)N * sizeof(int), stream);

    long n4 = (long)NH / 4;
    prep_kernel<<<1280, 256, 0, stream>>>(x, xB, n4, W1, W2, W1B, W2B, eidx, hist, E);

    if (NB <= 64) {
        block_scan_kernel<<<NB, 256, 0, stream>>>(hist, offsets, blockSums, N);
        scan_finalize_kernel<<<NB, 256, 0, stream>>>(blockSums, offsets, cursor, N, NB);
    } else {
        scan_kernel<<<1, 1024, 0, stream>>>(hist, offsets, cursor, N);
    }
    reorder_kernel<<<2048, 256, 0, stream>>>(eidx, cursor, srcSorted, E, partSize);
    aggregate_kernel<<<(N + 15) / 16, 256, 0, stream>>>(x, xB, offsets, srcSorted, eps, aggB, N);

    int gblocks = (N + 63) / 64;
    gemm_fused<<<gblocks, 256, 0, stream>>>(aggB, W1B, b1, W2B, b2, out, statSum, statSqs, N);

    bn_prep_kernel<<<1, HDIM, 0, stream>>>(statSum, statSqs, gamma, beta, bnScale, bnShift, N);
    bn_apply_kernel<<<(int)((n4 + 255) / 256), 256, 0, stream>>>(out, bnScale, bnShift, n4);
}